// Round 2
// baseline (1190.153 us; speedup 1.0000x reference)
//
#include <hip/hip_runtime.h>
#include <math.h>

#define NN 50000
#define NF 512
#define NHID 256
#define NCLASS 64
#define NHEADS 8

// ---------------- CSR build ----------------
__global__ void k_init_deg(int* deg) {
  int i = blockIdx.x * blockDim.x + threadIdx.x;
  if (i < NN) deg[i] = 1;  // self loop
}

__global__ void k_count(const int* __restrict__ dst, int E0, int* deg) {
  int i = blockIdx.x * blockDim.x + threadIdx.x;
  if (i < E0) atomicAdd(&deg[dst[i]], 1);
}

__global__ void k_scan(const int* __restrict__ deg, int* offs, int* cursor) {
  __shared__ int sdata[1024];
  __shared__ int srun;
  int tid = threadIdx.x;
  if (tid == 0) srun = 0;
  __syncthreads();
  for (int base = 0; base < NN; base += 1024) {
    int i = base + tid;
    int v = (i < NN) ? deg[i] : 0;
    sdata[tid] = v;
    __syncthreads();
    #pragma unroll
    for (int off = 1; off < 1024; off <<= 1) {
      int t = (tid >= off) ? sdata[tid - off] : 0;
      __syncthreads();
      sdata[tid] += t;
      __syncthreads();
    }
    int incl = sdata[tid];
    int run = srun;
    if (i < NN) { offs[i] = run + incl - v; cursor[i] = run + incl - v; }
    __syncthreads();
    if (tid == 1023) srun = run + incl;
    __syncthreads();
  }
  if (tid == 0) offs[NN] = srun;
}

__global__ void k_scatter(const int* __restrict__ src, const int* __restrict__ dst,
                          int E0, int* cursor, int* __restrict__ nbr) {
  int i = blockIdx.x * blockDim.x + threadIdx.x;
  if (i < E0) {
    int pos = atomicAdd(&cursor[dst[i]], 1);
    nbr[pos] = src[i];
  } else if (i < E0 + NN) {
    int v = i - E0;
    int pos = atomicAdd(&cursor[v], 1);
    nbr[pos] = v;
  }
}

// ---------------- fp32 tiled GEMM: C[rows,cols] = A[rows,K] * B[K,cols] ----------------
__global__ __launch_bounds__(256) void k_gemm(const float* __restrict__ A,
                                              const float* __restrict__ B,
                                              float* __restrict__ C,
                                              int rows, int K, int cols) {
  __shared__ float As[16][68];
  __shared__ float Bs[16][68];
  int t = threadIdx.x;
  int rowBase = blockIdx.x * 64;
  int colBase = blockIdx.y * 64;
  int tx = t & 15, ty = t >> 4;
  int ar = t >> 2, ak = (t & 3) << 2;
  int bk = t >> 4, bc = (t & 15) << 2;
  int arow = rowBase + ar;
  bool avalid = arow < rows;
  const float* Ap = A + (size_t)(avalid ? arow : 0) * K + ak;
  const float* Bp = B + (size_t)bk * cols + colBase + bc;
  float acc[4][4] = {};
  for (int k0 = 0; k0 < K; k0 += 16) {
    float4 av = avalid ? *(const float4*)(Ap + k0) : make_float4(0.f, 0.f, 0.f, 0.f);
    float4 bv = *(const float4*)(Bp + (size_t)k0 * cols);
    As[ak + 0][ar] = av.x;
    As[ak + 1][ar] = av.y;
    As[ak + 2][ar] = av.z;
    As[ak + 3][ar] = av.w;
    *(float4*)&Bs[bk][bc] = bv;
    __syncthreads();
    #pragma unroll
    for (int kk = 0; kk < 16; kk++) {
      float4 a4 = *(const float4*)&As[kk][ty << 2];
      float4 b4 = *(const float4*)&Bs[kk][tx << 2];
      acc[0][0] += a4.x * b4.x; acc[0][1] += a4.x * b4.y; acc[0][2] += a4.x * b4.z; acc[0][3] += a4.x * b4.w;
      acc[1][0] += a4.y * b4.x; acc[1][1] += a4.y * b4.y; acc[1][2] += a4.y * b4.z; acc[1][3] += a4.y * b4.w;
      acc[2][0] += a4.z * b4.x; acc[2][1] += a4.z * b4.y; acc[2][2] += a4.z * b4.z; acc[2][3] += a4.z * b4.w;
      acc[3][0] += a4.w * b4.x; acc[3][1] += a4.w * b4.y; acc[3][2] += a4.w * b4.z; acc[3][3] += a4.w * b4.w;
    }
    __syncthreads();
  }
  #pragma unroll
  for (int i = 0; i < 4; i++) {
    int r = rowBase + (ty << 2) + i;
    if (r < rows) {
      float4 o = make_float4(acc[i][0], acc[i][1], acc[i][2], acc[i][3]);
      *(float4*)(C + (size_t)r * cols + colBase + (tx << 2)) = o;
    }
  }
}

// ---------------- edge-score dots ----------------
template <int C>
__global__ void k_escore(const float* __restrict__ h, const float* __restrict__ asr,
                         const float* __restrict__ ads, float* __restrict__ es,
                         float* __restrict__ ed) {
  int idx = blockIdx.x * blockDim.x + threadIdx.x;  // n*8 + head
  if (idx >= NN * NHEADS) return;
  int hd = idx & 7;
  const float* row = h + (size_t)idx * C;
  float s = 0.f, d = 0.f;
  #pragma unroll
  for (int c = 0; c < C; c++) {
    float v = row[c];
    s += v * asr[hd * C + c];
    d += v * ads[hd * C + c];
  }
  es[idx] = s;
  ed[idx] = d;
}

// ---------------- per-edge softmax coefficients ----------------
// wave per node; lane = sub*8 + head; 8 lanes (sub=0..7) cover edges stride-8
// for one head. Online softmax per lane, butterfly-merge across sub lanes,
// then second sweep writes normalized coef[e*8+h] (wave writes 256B chunks).
__global__ __launch_bounds__(256) void k_coef(const int* __restrict__ offs,
                                              const int* __restrict__ nbr,
                                              const float* __restrict__ es,
                                              const float* __restrict__ ed,
                                              float* __restrict__ coef) {
  int node = blockIdx.x * 4 + (threadIdx.x >> 6);
  if (node >= NN) return;
  int lane = threadIdx.x & 63;
  int h = lane & 7;
  int sub = lane >> 3;
  int beg = offs[node], end = offs[node + 1];
  float edst = ed[node * NHEADS + h];
  float m = -1e30f, z = 0.f;
  for (int k = beg + sub; k < end; k += 8) {
    int s = nbr[k];
    float a = es[s * NHEADS + h] + edst;
    a = (a > 0.f) ? a : 0.2f * a;
    float mn = fmaxf(m, a);
    z = z * __expf(m - mn) + __expf(a - mn);
    m = mn;
  }
  #pragma unroll
  for (int o = 8; o < 64; o <<= 1) {
    float m2 = __shfl_xor(m, o);
    float z2 = __shfl_xor(z, o);
    float mn = fmaxf(m, m2);
    z = z * __expf(m - mn) + z2 * __expf(m2 - mn);
    m = mn;
  }
  float inv = 1.f / z;
  for (int k = beg + sub; k < end; k += 8) {
    int s = nbr[k];
    float a = es[s * NHEADS + h] + edst;
    a = (a > 0.f) ? a : 0.2f * a;
    coef[(size_t)k * NHEADS + h] = __expf(a - m) * inv;
  }
}

// ---------------- layer-1 aggregation: pure weighted gather ----------------
__global__ __launch_bounds__(256) void k_agg1(const int* __restrict__ offs,
                                              const int* __restrict__ nbr,
                                              const float* __restrict__ h1,
                                              const float* __restrict__ coef,
                                              const float* __restrict__ b1,
                                              float* __restrict__ out) {
  int node = blockIdx.x * 4 + (threadIdx.x >> 6);
  if (node >= NN) return;
  int lane = threadIdx.x & 63;
  int head = lane >> 3;
  int beg = offs[node], end = offs[node + 1];
  float4 acc = make_float4(0.f, 0.f, 0.f, 0.f);
  int k = beg;
  for (; k + 1 < end; k += 2) {
    int s0 = nbr[k], s1 = nbr[k + 1];
    float c0 = coef[(size_t)k * NHEADS + head];
    float c1 = coef[(size_t)(k + 1) * NHEADS + head];
    float4 v0 = *(const float4*)(h1 + (size_t)s0 * NHID + (lane << 2));
    float4 v1 = *(const float4*)(h1 + (size_t)s1 * NHID + (lane << 2));
    acc.x += c0 * v0.x + c1 * v1.x;
    acc.y += c0 * v0.y + c1 * v1.y;
    acc.z += c0 * v0.z + c1 * v1.z;
    acc.w += c0 * v0.w + c1 * v1.w;
  }
  if (k < end) {
    int s0 = nbr[k];
    float c0 = coef[(size_t)k * NHEADS + head];
    float4 v0 = *(const float4*)(h1 + (size_t)s0 * NHID + (lane << 2));
    acc.x += c0 * v0.x;
    acc.y += c0 * v0.y;
    acc.z += c0 * v0.z;
    acc.w += c0 * v0.w;
  }
  int col = lane << 2;
  float4 o;
  o.x = fmaxf(acc.x + b1[col + 0], 0.f);
  o.y = fmaxf(acc.y + b1[col + 1], 0.f);
  o.z = fmaxf(acc.z + b1[col + 2], 0.f);
  o.w = fmaxf(acc.w + b1[col + 3], 0.f);
  *(float4*)(out + (size_t)node * NHID + col) = o;
}

// ---------------- layer-2 aggregation + head-mean + bias + log_softmax ----------------
__global__ __launch_bounds__(256) void k_agg2(const int* __restrict__ offs,
                                              const int* __restrict__ nbr,
                                              const float* __restrict__ h2,
                                              const float* __restrict__ coef,
                                              const float* __restrict__ b2,
                                              float* __restrict__ out) {
  int node = blockIdx.x * 4 + (threadIdx.x >> 6);
  if (node >= NN) return;
  int lane = threadIdx.x & 63;  // class index
  float acc[8] = {};
  int beg = offs[node], end = offs[node + 1];
  int k = beg;
  for (; k + 1 < end; k += 2) {
    int s0 = nbr[k], s1 = nbr[k + 1];
    const float* r0 = h2 + (size_t)s0 * (NHEADS * NCLASS) + lane;
    const float* r1 = h2 + (size_t)s1 * (NHEADS * NCLASS) + lane;
    float4 ca0 = *(const float4*)(coef + (size_t)k * NHEADS);
    float4 cb0 = *(const float4*)(coef + (size_t)k * NHEADS + 4);
    float4 ca1 = *(const float4*)(coef + (size_t)(k + 1) * NHEADS);
    float4 cb1 = *(const float4*)(coef + (size_t)(k + 1) * NHEADS + 4);
    acc[0] += ca0.x * r0[0 * NCLASS] + ca1.x * r1[0 * NCLASS];
    acc[1] += ca0.y * r0[1 * NCLASS] + ca1.y * r1[1 * NCLASS];
    acc[2] += ca0.z * r0[2 * NCLASS] + ca1.z * r1[2 * NCLASS];
    acc[3] += ca0.w * r0[3 * NCLASS] + ca1.w * r1[3 * NCLASS];
    acc[4] += cb0.x * r0[4 * NCLASS] + cb1.x * r1[4 * NCLASS];
    acc[5] += cb0.y * r0[5 * NCLASS] + cb1.y * r1[5 * NCLASS];
    acc[6] += cb0.z * r0[6 * NCLASS] + cb1.z * r1[6 * NCLASS];
    acc[7] += cb0.w * r0[7 * NCLASS] + cb1.w * r1[7 * NCLASS];
  }
  if (k < end) {
    int s0 = nbr[k];
    const float* r0 = h2 + (size_t)s0 * (NHEADS * NCLASS) + lane;
    float4 ca0 = *(const float4*)(coef + (size_t)k * NHEADS);
    float4 cb0 = *(const float4*)(coef + (size_t)k * NHEADS + 4);
    acc[0] += ca0.x * r0[0 * NCLASS];
    acc[1] += ca0.y * r0[1 * NCLASS];
    acc[2] += ca0.z * r0[2 * NCLASS];
    acc[3] += ca0.w * r0[3 * NCLASS];
    acc[4] += cb0.x * r0[4 * NCLASS];
    acc[5] += cb0.y * r0[5 * NCLASS];
    acc[6] += cb0.z * r0[6 * NCLASS];
    acc[7] += cb0.w * r0[7 * NCLASS];
  }
  float val = 0.f;
  #pragma unroll
  for (int h = 0; h < 8; h++) val += acc[h];
  val = val * 0.125f + b2[lane];
  float mx = val;
  #pragma unroll
  for (int o = 32; o > 0; o >>= 1) mx = fmaxf(mx, __shfl_xor(mx, o));
  float ex = __expf(val - mx);
  float sm = ex;
  #pragma unroll
  for (int o = 32; o > 0; o >>= 1) sm += __shfl_xor(sm, o);
  out[(size_t)node * NCLASS + lane] = val - mx - __logf(sm);
}

// ---------------- launch ----------------
extern "C" void kernel_launch(void* const* d_in, const int* in_sizes, int n_in,
                              void* d_out, int out_size, void* d_ws, size_t ws_size,
                              hipStream_t stream) {
  const float* x   = (const float*)d_in[0];
  const int* eidx  = (const int*)d_in[1];
  const float* W1  = (const float*)d_in[2];
  const float* a1s = (const float*)d_in[3];
  const float* a1d = (const float*)d_in[4];
  const float* b1  = (const float*)d_in[5];
  const float* W2  = (const float*)d_in[6];
  const float* a2s = (const float*)d_in[7];
  const float* a2d = (const float*)d_in[8];
  const float* b2  = (const float*)d_in[9];
  const int E0 = in_sizes[1] / 2;
  const int* esrc = eidx;
  const int* edst = eidx + E0;
  const int E = E0 + NN;

  char* w = (char*)d_ws;
  auto carve = [&](size_t bytes) {
    void* p = (void*)w;
    w += (bytes + 255) & ~(size_t)255;
    return p;
  };
  int* deg     = (int*)carve((size_t)NN * 4);
  int* offs    = (int*)carve((size_t)(NN + 1) * 4);
  int* cursor  = (int*)carve((size_t)NN * 4);
  int* nbr     = (int*)carve((size_t)E * 4);
  float* h1    = (float*)carve((size_t)NN * NHID * 4);
  float* es1   = (float*)carve((size_t)NN * NHEADS * 4);
  float* ed1   = (float*)carve((size_t)NN * NHEADS * 4);
  float* out1  = (float*)carve((size_t)NN * NHID * 4);
  float* h2    = (float*)carve((size_t)NN * NHEADS * NCLASS * 4);
  float* es2   = (float*)carve((size_t)NN * NHEADS * 4);
  float* ed2   = (float*)carve((size_t)NN * NHEADS * 4);
  float* coef  = (float*)carve((size_t)E * NHEADS * 4);

  // CSR build
  k_init_deg<<<(NN + 255) / 256, 256, 0, stream>>>(deg);
  k_count<<<(E0 + 255) / 256, 256, 0, stream>>>(edst, E0, deg);
  k_scan<<<1, 1024, 0, stream>>>(deg, offs, cursor);
  k_scatter<<<(E0 + NN + 255) / 256, 256, 0, stream>>>(esrc, edst, E0, cursor, nbr);

  // layer 1
  k_gemm<<<dim3((NN + 63) / 64, NHID / 64), 256, 0, stream>>>(x, W1, h1, NN, NF, NHID);
  k_escore<32><<<(NN * NHEADS + 255) / 256, 256, 0, stream>>>(h1, a1s, a1d, es1, ed1);
  k_coef<<<(NN + 3) / 4, 256, 0, stream>>>(offs, nbr, es1, ed1, coef);
  k_agg1<<<(NN + 3) / 4, 256, 0, stream>>>(offs, nbr, h1, coef, b1, out1);

  // layer 2
  k_gemm<<<dim3((NN + 63) / 64, (NHEADS * NCLASS) / 64), 256, 0, stream>>>(
      out1, W2, h2, NN, NHID, NHEADS * NCLASS);
  k_escore<64><<<(NN * NHEADS + 255) / 256, 256, 0, stream>>>(h2, a2s, a2d, es2, ed2);
  k_coef<<<(NN + 3) / 4, 256, 0, stream>>>(offs, nbr, es2, ed2, coef);
  k_agg2<<<(NN + 3) / 4, 256, 0, stream>>>(offs, nbr, h2, coef, b2, (float*)d_out);
}

// Round 3
// 993.556 us; speedup vs baseline: 1.1979x; 1.1979x over previous
//
#include <hip/hip_runtime.h>
#include <math.h>

#define NN 50000
#define NF 512
#define NHID 256
#define NCLASS 64
#define NHEADS 8

typedef __attribute__((ext_vector_type(8))) short bf16x8;
typedef __attribute__((ext_vector_type(4))) float f32x4;

static __device__ __forceinline__ unsigned short f2bf(float f) {
  unsigned int u = __float_as_uint(f);
  unsigned int r = (u + 0x7fffu + ((u >> 16) & 1u)) >> 16;
  return (unsigned short)r;
}

// ---------------- CSR build ----------------
__global__ void k_init_deg(int* deg) {
  int i = blockIdx.x * blockDim.x + threadIdx.x;
  if (i < NN) deg[i] = 1;  // self loop
}

__global__ void k_count(const int* __restrict__ dst, int E0, int* deg) {
  int i = blockIdx.x * blockDim.x + threadIdx.x;
  if (i < E0) atomicAdd(&deg[dst[i]], 1);
}

// shuffle-based scan: 16 waves, 2 barriers per 1024-chunk
__global__ __launch_bounds__(1024) void k_scan(const int* __restrict__ deg, int* offs,
                                               int* cursor) {
  __shared__ int wbase[16];
  __shared__ int srun;
  int tid = threadIdx.x;
  int lane = tid & 63;
  int wv = tid >> 6;
  if (tid == 0) srun = 0;
  __syncthreads();
  for (int base = 0; base < NN; base += 1024) {
    int i = base + tid;
    int v = (i < NN) ? deg[i] : 0;
    int s = v;
    #pragma unroll
    for (int o = 1; o < 64; o <<= 1) {
      int t = __shfl_up(s, o);
      if (lane >= o) s += t;
    }
    if (lane == 63) wbase[wv] = s;
    __syncthreads();
    if (tid == 0) {
      int run = srun;
      #pragma unroll
      for (int w2 = 0; w2 < 16; w2++) {
        int t = wbase[w2];
        wbase[w2] = run;
        run += t;
      }
      srun = run;
    }
    __syncthreads();
    if (i < NN) {
      int e = wbase[wv] + s - v;  // exclusive
      offs[i] = e;
      cursor[i] = e;
    }
  }
  __syncthreads();
  if (tid == 0) offs[NN] = srun;
}

__global__ void k_scatter(const int* __restrict__ src, const int* __restrict__ dst,
                          int E0, int* cursor, int* __restrict__ nbr) {
  int i = blockIdx.x * blockDim.x + threadIdx.x;
  if (i < E0) {
    int pos = atomicAdd(&cursor[dst[i]], 1);
    nbr[pos] = src[i];
  } else if (i < E0 + NN) {
    int v = i - E0;
    int pos = atomicAdd(&cursor[v], 1);
    nbr[pos] = v;
  }
}

// ---------------- casts ----------------
__global__ void k_cast4(const float* __restrict__ in, unsigned short* __restrict__ out,
                        int n4) {
  int i = blockIdx.x * blockDim.x + threadIdx.x;
  if (i >= n4) return;
  float4 v = *(const float4*)(in + (size_t)i * 4);
  ushort4 o;
  o.x = f2bf(v.x); o.y = f2bf(v.y); o.z = f2bf(v.z); o.w = f2bf(v.w);
  *(ushort4*)(out + (size_t)i * 4) = o;
}

// W [K, cols] fp32 -> Wt [cols, K] bf16
__global__ void k_castWt(const float* __restrict__ W, unsigned short* __restrict__ Wt,
                         int K, int cols) {
  int i = blockIdx.x * blockDim.x + threadIdx.x;
  if (i >= K * cols) return;
  int k = i / cols, c = i % cols;
  Wt[(size_t)c * K + k] = f2bf(W[i]);
}

// ---------------- bf16 MFMA GEMM ----------------
// A [rows,K] bf16 row-major, Bt [cols,K] bf16, C [rows,cols] fp32.
// Wave computes 16 rows x 64 cols; 4 waves/block = 64 rows x 64 cols.
// rows % 16 == 0, K % 32 == 0, cols % 64 == 0.
__global__ __launch_bounds__(256) void k_gemm_bf(const unsigned short* __restrict__ A,
                                                 const unsigned short* __restrict__ Bt,
                                                 float* __restrict__ C,
                                                 int rowStrips, int K, int cols) {
  int rs = blockIdx.x * 4 + (threadIdx.x >> 6);
  if (rs >= rowStrips) return;
  int rb = rs * 16;
  int cb = blockIdx.y * 64;
  int lane = threadIdx.x & 63;
  int quad = lane >> 4;
  int sixt = lane & 15;
  const unsigned short* Ap = A + (size_t)(rb + sixt) * K + quad * 8;
  const unsigned short* Bp = Bt + (size_t)(cb + sixt) * K + quad * 8;
  f32x4 acc0 = {}, acc1 = {}, acc2 = {}, acc3 = {};
  for (int k0 = 0; k0 < K; k0 += 32) {
    bf16x8 a = *(const bf16x8*)(Ap + k0);
    bf16x8 b0 = *(const bf16x8*)(Bp + k0);
    bf16x8 b1 = *(const bf16x8*)(Bp + (size_t)16 * K + k0);
    bf16x8 b2 = *(const bf16x8*)(Bp + (size_t)32 * K + k0);
    bf16x8 b3 = *(const bf16x8*)(Bp + (size_t)48 * K + k0);
    acc0 = __builtin_amdgcn_mfma_f32_16x16x32_bf16(a, b0, acc0, 0, 0, 0);
    acc1 = __builtin_amdgcn_mfma_f32_16x16x32_bf16(a, b1, acc1, 0, 0, 0);
    acc2 = __builtin_amdgcn_mfma_f32_16x16x32_bf16(a, b2, acc2, 0, 0, 0);
    acc3 = __builtin_amdgcn_mfma_f32_16x16x32_bf16(a, b3, acc3, 0, 0, 0);
  }
  float* Cp = C + (size_t)(rb + quad * 4) * cols + cb + sixt;
  #pragma unroll
  for (int r = 0; r < 4; r++) {
    float* row = Cp + (size_t)r * cols;
    row[0] = acc0[r];
    row[16] = acc1[r];
    row[32] = acc2[r];
    row[48] = acc3[r];
  }
}

// ---------------- edge-score dots ----------------
template <int C>
__global__ void k_escore(const float* __restrict__ h, const float* __restrict__ asr,
                         const float* __restrict__ ads, float* __restrict__ es,
                         float* __restrict__ ed) {
  int idx = blockIdx.x * blockDim.x + threadIdx.x;  // n*8 + head
  if (idx >= NN * NHEADS) return;
  int hd = idx & 7;
  const float* row = h + (size_t)idx * C;
  float s = 0.f, d = 0.f;
  #pragma unroll
  for (int c = 0; c < C; c++) {
    float v = row[c];
    s += v * asr[hd * C + c];
    d += v * ads[hd * C + c];
  }
  es[idx] = s;
  ed[idx] = d;
}

// ---------------- per-edge softmax coefficients ----------------
__global__ __launch_bounds__(256) void k_coef(const int* __restrict__ offs,
                                              const int* __restrict__ nbr,
                                              const float* __restrict__ es,
                                              const float* __restrict__ ed,
                                              float* __restrict__ coef) {
  int node = blockIdx.x * 4 + (threadIdx.x >> 6);
  if (node >= NN) return;
  int lane = threadIdx.x & 63;
  int h = lane & 7;
  int sub = lane >> 3;
  int beg = offs[node], end = offs[node + 1];
  float edst = ed[node * NHEADS + h];
  float m = -1e30f, z = 0.f;
  for (int k = beg + sub; k < end; k += 8) {
    int s = nbr[k];
    float a = es[s * NHEADS + h] + edst;
    a = (a > 0.f) ? a : 0.2f * a;
    float mn = fmaxf(m, a);
    z = z * __expf(m - mn) + __expf(a - mn);
    m = mn;
  }
  #pragma unroll
  for (int o = 8; o < 64; o <<= 1) {
    float m2 = __shfl_xor(m, o);
    float z2 = __shfl_xor(z, o);
    float mn = fmaxf(m, m2);
    z = z * __expf(m - mn) + z2 * __expf(m2 - mn);
    m = mn;
  }
  float inv = 1.f / z;
  for (int k = beg + sub; k < end; k += 8) {
    int s = nbr[k];
    float a = es[s * NHEADS + h] + edst;
    a = (a > 0.f) ? a : 0.2f * a;
    coef[(size_t)k * NHEADS + h] = __expf(a - m) * inv;
  }
}

// ---------------- layer-1 aggregation (writes bf16 for GEMM2) ----------------
__global__ __launch_bounds__(256) void k_agg1(const int* __restrict__ offs,
                                              const int* __restrict__ nbr,
                                              const float* __restrict__ h1,
                                              const float* __restrict__ coef,
                                              const float* __restrict__ b1,
                                              unsigned short* __restrict__ out) {
  int node = blockIdx.x * 4 + (threadIdx.x >> 6);
  if (node >= NN) return;
  int lane = threadIdx.x & 63;
  int head = lane >> 3;
  int beg = offs[node], end = offs[node + 1];
  float4 acc = make_float4(0.f, 0.f, 0.f, 0.f);
  int k = beg;
  for (; k + 1 < end; k += 2) {
    int s0 = nbr[k], s1 = nbr[k + 1];
    float c0 = coef[(size_t)k * NHEADS + head];
    float c1 = coef[(size_t)(k + 1) * NHEADS + head];
    float4 v0 = *(const float4*)(h1 + (size_t)s0 * NHID + (lane << 2));
    float4 v1 = *(const float4*)(h1 + (size_t)s1 * NHID + (lane << 2));
    acc.x += c0 * v0.x + c1 * v1.x;
    acc.y += c0 * v0.y + c1 * v1.y;
    acc.z += c0 * v0.z + c1 * v1.z;
    acc.w += c0 * v0.w + c1 * v1.w;
  }
  if (k < end) {
    int s0 = nbr[k];
    float c0 = coef[(size_t)k * NHEADS + head];
    float4 v0 = *(const float4*)(h1 + (size_t)s0 * NHID + (lane << 2));
    acc.x += c0 * v0.x;
    acc.y += c0 * v0.y;
    acc.z += c0 * v0.z;
    acc.w += c0 * v0.w;
  }
  int col = lane << 2;
  ushort4 o;
  o.x = f2bf(fmaxf(acc.x + b1[col + 0], 0.f));
  o.y = f2bf(fmaxf(acc.y + b1[col + 1], 0.f));
  o.z = f2bf(fmaxf(acc.z + b1[col + 2], 0.f));
  o.w = f2bf(fmaxf(acc.w + b1[col + 3], 0.f));
  *(ushort4*)(out + (size_t)node * NHID + col) = o;
}

// ---------------- layer-2 aggregation + head-mean + bias + log_softmax ----------------
__global__ __launch_bounds__(256) void k_agg2(const int* __restrict__ offs,
                                              const int* __restrict__ nbr,
                                              const float* __restrict__ h2,
                                              const float* __restrict__ coef,
                                              const float* __restrict__ b2,
                                              float* __restrict__ out) {
  int node = blockIdx.x * 4 + (threadIdx.x >> 6);
  if (node >= NN) return;
  int lane = threadIdx.x & 63;  // class index
  float acc[8] = {};
  int beg = offs[node], end = offs[node + 1];
  int k = beg;
  for (; k + 1 < end; k += 2) {
    int s0 = nbr[k], s1 = nbr[k + 1];
    const float* r0 = h2 + (size_t)s0 * (NHEADS * NCLASS) + lane;
    const float* r1 = h2 + (size_t)s1 * (NHEADS * NCLASS) + lane;
    float4 ca0 = *(const float4*)(coef + (size_t)k * NHEADS);
    float4 cb0 = *(const float4*)(coef + (size_t)k * NHEADS + 4);
    float4 ca1 = *(const float4*)(coef + (size_t)(k + 1) * NHEADS);
    float4 cb1 = *(const float4*)(coef + (size_t)(k + 1) * NHEADS + 4);
    acc[0] += ca0.x * r0[0 * NCLASS] + ca1.x * r1[0 * NCLASS];
    acc[1] += ca0.y * r0[1 * NCLASS] + ca1.y * r1[1 * NCLASS];
    acc[2] += ca0.z * r0[2 * NCLASS] + ca1.z * r1[2 * NCLASS];
    acc[3] += ca0.w * r0[3 * NCLASS] + ca1.w * r1[3 * NCLASS];
    acc[4] += cb0.x * r0[4 * NCLASS] + cb1.x * r1[4 * NCLASS];
    acc[5] += cb0.y * r0[5 * NCLASS] + cb1.y * r1[5 * NCLASS];
    acc[6] += cb0.z * r0[6 * NCLASS] + cb1.z * r1[6 * NCLASS];
    acc[7] += cb0.w * r0[7 * NCLASS] + cb1.w * r1[7 * NCLASS];
  }
  if (k < end) {
    int s0 = nbr[k];
    const float* r0 = h2 + (size_t)s0 * (NHEADS * NCLASS) + lane;
    float4 ca0 = *(const float4*)(coef + (size_t)k * NHEADS);
    float4 cb0 = *(const float4*)(coef + (size_t)k * NHEADS + 4);
    acc[0] += ca0.x * r0[0 * NCLASS];
    acc[1] += ca0.y * r0[1 * NCLASS];
    acc[2] += ca0.z * r0[2 * NCLASS];
    acc[3] += ca0.w * r0[3 * NCLASS];
    acc[4] += cb0.x * r0[4 * NCLASS];
    acc[5] += cb0.y * r0[5 * NCLASS];
    acc[6] += cb0.z * r0[6 * NCLASS];
    acc[7] += cb0.w * r0[7 * NCLASS];
  }
  float val = 0.f;
  #pragma unroll
  for (int h = 0; h < 8; h++) val += acc[h];
  val = val * 0.125f + b2[lane];
  float mx = val;
  #pragma unroll
  for (int o = 32; o > 0; o >>= 1) mx = fmaxf(mx, __shfl_xor(mx, o));
  float ex = __expf(val - mx);
  float sm = ex;
  #pragma unroll
  for (int o = 32; o > 0; o >>= 1) sm += __shfl_xor(sm, o);
  out[(size_t)node * NCLASS + lane] = val - mx - __logf(sm);
}

// ---------------- launch ----------------
extern "C" void kernel_launch(void* const* d_in, const int* in_sizes, int n_in,
                              void* d_out, int out_size, void* d_ws, size_t ws_size,
                              hipStream_t stream) {
  const float* x   = (const float*)d_in[0];
  const int* eidx  = (const int*)d_in[1];
  const float* W1  = (const float*)d_in[2];
  const float* a1s = (const float*)d_in[3];
  const float* a1d = (const float*)d_in[4];
  const float* b1  = (const float*)d_in[5];
  const float* W2  = (const float*)d_in[6];
  const float* a2s = (const float*)d_in[7];
  const float* a2d = (const float*)d_in[8];
  const float* b2  = (const float*)d_in[9];
  const int E0 = in_sizes[1] / 2;
  const int* esrc = eidx;
  const int* edst = eidx + E0;
  const int E = E0 + NN;

  char* w = (char*)d_ws;
  auto carve = [&](size_t bytes) {
    void* p = (void*)w;
    w += (bytes + 255) & ~(size_t)255;
    return p;
  };
  int* deg      = (int*)carve((size_t)NN * 4);
  int* offs     = (int*)carve((size_t)(NN + 1) * 4);
  int* cursor   = (int*)carve((size_t)NN * 4);
  int* nbr      = (int*)carve((size_t)E * 4);
  float* h1     = (float*)carve((size_t)NN * NHID * 4);
  float* es1    = (float*)carve((size_t)NN * NHEADS * 4);
  float* ed1    = (float*)carve((size_t)NN * NHEADS * 4);
  float* h2     = (float*)carve((size_t)NN * NHEADS * NCLASS * 4);
  float* coef   = (float*)carve((size_t)E * NHEADS * 4);
  unsigned short* xbf   = (unsigned short*)carve((size_t)NN * NF * 2);
  unsigned short* W1t   = (unsigned short*)carve((size_t)NF * NHID * 2);
  unsigned short* W2t   = (unsigned short*)carve((size_t)NHID * NHEADS * NCLASS * 2);
  unsigned short* out1b = (unsigned short*)carve((size_t)NN * NHID * 2);

  // CSR build
  k_init_deg<<<(NN + 255) / 256, 256, 0, stream>>>(deg);
  k_count<<<(E0 + 255) / 256, 256, 0, stream>>>(edst, E0, deg);
  k_scan<<<1, 1024, 0, stream>>>(deg, offs, cursor);
  k_scatter<<<(E0 + NN + 255) / 256, 256, 0, stream>>>(esrc, edst, E0, cursor, nbr);

  // casts
  k_cast4<<<(NN * NF / 4 + 255) / 256, 256, 0, stream>>>(x, xbf, NN * NF / 4);
  k_castWt<<<(NF * NHID + 255) / 256, 256, 0, stream>>>(W1, W1t, NF, NHID);
  k_castWt<<<(NHID * NHEADS * NCLASS + 255) / 256, 256, 0, stream>>>(W2, W2t, NHID,
                                                                     NHEADS * NCLASS);

  // layer 1:  h1 = x @ W1  (50000x512 @ 512x256)
  k_gemm_bf<<<dim3((NN / 16 + 3) / 4, NHID / 64), 256, 0, stream>>>(xbf, W1t, h1,
                                                                    NN / 16, NF, NHID);
  k_escore<32><<<(NN * NHEADS + 255) / 256, 256, 0, stream>>>(h1, a1s, a1d, es1, ed1);
  k_coef<<<(NN + 3) / 4, 256, 0, stream>>>(offs, nbr, es1, ed1, coef);
  k_agg1<<<(NN + 3) / 4, 256, 0, stream>>>(offs, nbr, h1, coef, b1, out1b);

  // layer 2:  h2 = out1 @ W2  (50000x256 @ 256x512)
  k_gemm_bf<<<dim3((NN / 16 + 3) / 4, (NHEADS * NCLASS) / 64), 256, 0, stream>>>(
      out1b, W2t, h2, NN / 16, NHID, NHEADS * NCLASS);
  k_escore<64><<<(NN * NHEADS + 255) / 256, 256, 0, stream>>>(h2, a2s, a2d, es1, ed1);
  k_coef<<<(NN + 3) / 4, 256, 0, stream>>>(offs, nbr, es1, ed1, coef);
  k_agg2<<<(NN + 3) / 4, 256, 0, stream>>>(offs, nbr, h2, coef, b2, (float*)d_out);
}

// Round 4
// 824.058 us; speedup vs baseline: 1.4443x; 1.2057x over previous
//
#include <hip/hip_runtime.h>
#include <math.h>

#define NN 50000
#define NF 512
#define NHID 256
#define NCLASS 64
#define NHEADS 8

typedef __attribute__((ext_vector_type(8))) short bf16x8;
typedef __attribute__((ext_vector_type(4))) float f32x4;

static __device__ __forceinline__ unsigned short f2bf(float f) {
  unsigned int u = __float_as_uint(f);
  unsigned int r = (u + 0x7fffu + ((u >> 16) & 1u)) >> 16;
  return (unsigned short)r;
}
static __device__ __forceinline__ float bf2f(unsigned short u) {
  return __uint_as_float(((unsigned int)u) << 16);
}
// unpack a uint holding two bf16 (lo = even element, hi = odd element)
static __device__ __forceinline__ float2 bfpair(unsigned int u) {
  return make_float2(__uint_as_float(u << 16), __uint_as_float(u & 0xffff0000u));
}

// ---------------- CSR build ----------------
__global__ void k_init_deg(int* deg) {
  int i = blockIdx.x * blockDim.x + threadIdx.x;
  if (i < NN) deg[i] = 1;  // self loop
}

__global__ void k_count(const int* __restrict__ dst, int E0, int* deg) {
  int i = blockIdx.x * blockDim.x + threadIdx.x;
  if (i < E0) atomicAdd(&deg[dst[i]], 1);
}

__global__ __launch_bounds__(1024) void k_scan(const int* __restrict__ deg, int* offs,
                                               int* cursor) {
  __shared__ int wbase[16];
  __shared__ int srun;
  int tid = threadIdx.x;
  int lane = tid & 63;
  int wv = tid >> 6;
  if (tid == 0) srun = 0;
  __syncthreads();
  for (int base = 0; base < NN; base += 1024) {
    int i = base + tid;
    int v = (i < NN) ? deg[i] : 0;
    int s = v;
    #pragma unroll
    for (int o = 1; o < 64; o <<= 1) {
      int t = __shfl_up(s, o);
      if (lane >= o) s += t;
    }
    if (lane == 63) wbase[wv] = s;
    __syncthreads();
    if (tid == 0) {
      int run = srun;
      #pragma unroll
      for (int w2 = 0; w2 < 16; w2++) {
        int t = wbase[w2];
        wbase[w2] = run;
        run += t;
      }
      srun = run;
    }
    __syncthreads();
    if (i < NN) {
      int e = wbase[wv] + s - v;  // exclusive
      offs[i] = e;
      cursor[i] = e;
    }
  }
  __syncthreads();
  if (tid == 0) offs[NN] = srun;
}

__global__ void k_scatter(const int* __restrict__ src, const int* __restrict__ dst,
                          int E0, int* cursor, int* __restrict__ nbr) {
  int i = blockIdx.x * blockDim.x + threadIdx.x;
  if (i < E0) {
    int pos = atomicAdd(&cursor[dst[i]], 1);
    nbr[pos] = src[i];
  } else if (i < E0 + NN) {
    int v = i - E0;
    int pos = atomicAdd(&cursor[v], 1);
    nbr[pos] = v;
  }
}

// ---------------- casts ----------------
__global__ void k_cast4(const float* __restrict__ in, unsigned short* __restrict__ out,
                        int n4) {
  int i = blockIdx.x * blockDim.x + threadIdx.x;
  if (i >= n4) return;
  float4 v = *(const float4*)(in + (size_t)i * 4);
  ushort4 o;
  o.x = f2bf(v.x); o.y = f2bf(v.y); o.z = f2bf(v.z); o.w = f2bf(v.w);
  *(ushort4*)(out + (size_t)i * 4) = o;
}

// W1 [K, cols] fp32 -> Wt [cols, K] bf16 (plain transpose)
__global__ void k_castWt(const float* __restrict__ W, unsigned short* __restrict__ Wt,
                         int K, int cols) {
  int i = blockIdx.x * blockDim.x + threadIdx.x;
  if (i >= K * cols) return;
  int k = i / cols, c = i % cols;
  Wt[(size_t)c * K + k] = f2bf(W[i]);
}

// W2 [K, h, c] fp32 -> Wt [c*8+h, K] bf16 (transpose + head/class permute so that
// h2 lands in [node][class][head] layout)
__global__ void k_castWt_perm(const float* __restrict__ W, unsigned short* __restrict__ Wt,
                              int K) {
  int i = blockIdx.x * blockDim.x + threadIdx.x;
  if (i >= K * NHEADS * NCLASS) return;
  int k = i / (NHEADS * NCLASS);
  int rem = i % (NHEADS * NCLASS);
  int h = rem / NCLASS, c = rem % NCLASS;
  Wt[(size_t)(c * NHEADS + h) * K + k] = f2bf(W[i]);
}

// ---------------- bf16 MFMA GEMM, bf16 output ----------------
// A [rows,K] bf16 row-major, Bt [cols,K] bf16, C [rows,cols] bf16.
// Wave computes 16 rows x 64 cols. rows%16==0, K%32==0, cols%64==0.
__global__ __launch_bounds__(256) void k_gemm_bf(const unsigned short* __restrict__ A,
                                                 const unsigned short* __restrict__ Bt,
                                                 unsigned short* __restrict__ C,
                                                 int rowStrips, int K, int cols) {
  int rs = blockIdx.x * 4 + (threadIdx.x >> 6);
  if (rs >= rowStrips) return;
  int rb = rs * 16;
  int cb = blockIdx.y * 64;
  int lane = threadIdx.x & 63;
  int quad = lane >> 4;
  int sixt = lane & 15;
  const unsigned short* Ap = A + (size_t)(rb + sixt) * K + quad * 8;
  const unsigned short* Bp = Bt + (size_t)(cb + sixt) * K + quad * 8;
  f32x4 acc0 = {}, acc1 = {}, acc2 = {}, acc3 = {};
  for (int k0 = 0; k0 < K; k0 += 32) {
    bf16x8 a = *(const bf16x8*)(Ap + k0);
    bf16x8 b0 = *(const bf16x8*)(Bp + k0);
    bf16x8 b1 = *(const bf16x8*)(Bp + (size_t)16 * K + k0);
    bf16x8 b2 = *(const bf16x8*)(Bp + (size_t)32 * K + k0);
    bf16x8 b3 = *(const bf16x8*)(Bp + (size_t)48 * K + k0);
    acc0 = __builtin_amdgcn_mfma_f32_16x16x32_bf16(a, b0, acc0, 0, 0, 0);
    acc1 = __builtin_amdgcn_mfma_f32_16x16x32_bf16(a, b1, acc1, 0, 0, 0);
    acc2 = __builtin_amdgcn_mfma_f32_16x16x32_bf16(a, b2, acc2, 0, 0, 0);
    acc3 = __builtin_amdgcn_mfma_f32_16x16x32_bf16(a, b3, acc3, 0, 0, 0);
  }
  unsigned short* Cp = C + (size_t)(rb + quad * 4) * cols + cb + sixt;
  #pragma unroll
  for (int r = 0; r < 4; r++) {
    unsigned short* row = Cp + (size_t)r * cols;
    row[0] = f2bf(acc0[r]);
    row[16] = f2bf(acc1[r]);
    row[32] = f2bf(acc2[r]);
    row[48] = f2bf(acc3[r]);
  }
}

// ---------------- edge-score dots, contiguous layout (layer 1) ----------------
// h [n][head*C + c] bf16; thread = (n, head)
template <int C>
__global__ void k_escore_c(const unsigned short* __restrict__ h,
                           const float* __restrict__ asr, const float* __restrict__ ads,
                           float* __restrict__ es, float* __restrict__ ed) {
  int idx = blockIdx.x * blockDim.x + threadIdx.x;  // n*8 + head
  if (idx >= NN * NHEADS) return;
  int hd = idx & 7;
  const unsigned short* row = h + (size_t)idx * C;
  float s = 0.f, d = 0.f;
  #pragma unroll
  for (int c8 = 0; c8 < C / 8; c8++) {
    uint4 raw = *(const uint4*)(row + c8 * 8);
    float2 p0 = bfpair(raw.x), p1 = bfpair(raw.y), p2 = bfpair(raw.z), p3 = bfpair(raw.w);
    const float* as_ = asr + hd * C + c8 * 8;
    const float* ad_ = ads + hd * C + c8 * 8;
    s += p0.x * as_[0] + p0.y * as_[1] + p1.x * as_[2] + p1.y * as_[3] +
         p2.x * as_[4] + p2.y * as_[5] + p3.x * as_[6] + p3.y * as_[7];
    d += p0.x * ad_[0] + p0.y * ad_[1] + p1.x * ad_[2] + p1.y * ad_[3] +
         p2.x * ad_[4] + p2.y * ad_[5] + p3.x * ad_[6] + p3.y * ad_[7];
  }
  es[idx] = s;
  ed[idx] = d;
}

// ---------------- edge-score dots, permuted layout (layer 2) ----------------
// h [n][c*8 + head] bf16; thread = (n, head); a [h][c]
__global__ void k_escore_p(const unsigned short* __restrict__ h,
                           const float* __restrict__ asr, const float* __restrict__ ads,
                           float* __restrict__ es, float* __restrict__ ed) {
  int idx = blockIdx.x * blockDim.x + threadIdx.x;  // n*8 + head
  if (idx >= NN * NHEADS) return;
  int hd = idx & 7;
  int n = idx >> 3;
  const unsigned short* row = h + (size_t)n * (NHEADS * NCLASS) + hd;
  float s = 0.f, d = 0.f;
  #pragma unroll
  for (int c = 0; c < NCLASS; c++) {
    float v = bf2f(row[c * NHEADS]);
    s += v * asr[hd * NCLASS + c];
    d += v * ads[hd * NCLASS + c];
  }
  es[idx] = s;
  ed[idx] = d;
}

// ---------------- per-edge softmax coefficients ----------------
__global__ __launch_bounds__(256) void k_coef(const int* __restrict__ offs,
                                              const int* __restrict__ nbr,
                                              const float* __restrict__ es,
                                              const float* __restrict__ ed,
                                              float* __restrict__ coef) {
  int node = blockIdx.x * 4 + (threadIdx.x >> 6);
  if (node >= NN) return;
  int lane = threadIdx.x & 63;
  int h = lane & 7;
  int sub = lane >> 3;
  int beg = offs[node], end = offs[node + 1];
  float edst = ed[node * NHEADS + h];
  float m = -1e30f, z = 0.f;
  for (int k = beg + sub; k < end; k += 8) {
    int s = nbr[k];
    float a = es[s * NHEADS + h] + edst;
    a = (a > 0.f) ? a : 0.2f * a;
    float mn = fmaxf(m, a);
    z = z * __expf(m - mn) + __expf(a - mn);
    m = mn;
  }
  #pragma unroll
  for (int o = 8; o < 64; o <<= 1) {
    float m2 = __shfl_xor(m, o);
    float z2 = __shfl_xor(z, o);
    float mn = fmaxf(m, m2);
    z = z * __expf(m - mn) + z2 * __expf(m2 - mn);
    m = mn;
  }
  float inv = 1.f / z;
  for (int k = beg + sub; k < end; k += 8) {
    int s = nbr[k];
    float a = es[s * NHEADS + h] + edst;
    a = (a > 0.f) ? a : 0.2f * a;
    coef[(size_t)k * NHEADS + h] = __expf(a - m) * inv;
  }
}

// ---------------- layer-1 aggregation: bf16 gather -> bf16 out ----------------
__global__ __launch_bounds__(256) void k_agg1(const int* __restrict__ offs,
                                              const int* __restrict__ nbr,
                                              const unsigned short* __restrict__ h1,
                                              const float* __restrict__ coef,
                                              const float* __restrict__ b1,
                                              unsigned short* __restrict__ out) {
  int node = blockIdx.x * 4 + (threadIdx.x >> 6);
  if (node >= NN) return;
  int lane = threadIdx.x & 63;
  int head = lane >> 3;
  int beg = offs[node], end = offs[node + 1];
  float4 acc = make_float4(0.f, 0.f, 0.f, 0.f);
  int k = beg;
  for (; k + 1 < end; k += 2) {
    int s0 = nbr[k], s1 = nbr[k + 1];
    float c0 = coef[(size_t)k * NHEADS + head];
    float c1 = coef[(size_t)(k + 1) * NHEADS + head];
    uint2 r0 = *(const uint2*)(h1 + (size_t)s0 * NHID + (lane << 2));
    uint2 r1 = *(const uint2*)(h1 + (size_t)s1 * NHID + (lane << 2));
    float2 a0 = bfpair(r0.x), a1 = bfpair(r0.y);
    float2 b0 = bfpair(r1.x), b1_ = bfpair(r1.y);
    acc.x += c0 * a0.x + c1 * b0.x;
    acc.y += c0 * a0.y + c1 * b0.y;
    acc.z += c0 * a1.x + c1 * b1_.x;
    acc.w += c0 * a1.y + c1 * b1_.y;
  }
  if (k < end) {
    int s0 = nbr[k];
    float c0 = coef[(size_t)k * NHEADS + head];
    uint2 r0 = *(const uint2*)(h1 + (size_t)s0 * NHID + (lane << 2));
    float2 a0 = bfpair(r0.x), a1 = bfpair(r0.y);
    acc.x += c0 * a0.x;
    acc.y += c0 * a0.y;
    acc.z += c0 * a1.x;
    acc.w += c0 * a1.y;
  }
  int col = lane << 2;
  ushort4 o;
  o.x = f2bf(fmaxf(acc.x + b1[col + 0], 0.f));
  o.y = f2bf(fmaxf(acc.y + b1[col + 1], 0.f));
  o.z = f2bf(fmaxf(acc.z + b1[col + 2], 0.f));
  o.w = f2bf(fmaxf(acc.w + b1[col + 3], 0.f));
  *(ushort4*)(out + (size_t)node * NHID + col) = o;
}

// ---------------- layer-2 aggregation + head-mean + bias + log_softmax ----------------
// h2 permuted [n][c*8+h] bf16: lane=class loads its 8 heads as one uint4 (16B).
__global__ __launch_bounds__(256) void k_agg2(const int* __restrict__ offs,
                                              const int* __restrict__ nbr,
                                              const unsigned short* __restrict__ h2,
                                              const float* __restrict__ coef,
                                              const float* __restrict__ b2,
                                              float* __restrict__ out) {
  int node = blockIdx.x * 4 + (threadIdx.x >> 6);
  if (node >= NN) return;
  int lane = threadIdx.x & 63;  // class index
  float acc[8] = {};
  int beg = offs[node], end = offs[node + 1];
  int k = beg;
  for (; k + 1 < end; k += 2) {
    int s0 = nbr[k], s1 = nbr[k + 1];
    uint4 r0 = *(const uint4*)(h2 + (size_t)s0 * (NHEADS * NCLASS) + (lane << 3));
    uint4 r1 = *(const uint4*)(h2 + (size_t)s1 * (NHEADS * NCLASS) + (lane << 3));
    float4 ca0 = *(const float4*)(coef + (size_t)k * NHEADS);
    float4 cb0 = *(const float4*)(coef + (size_t)k * NHEADS + 4);
    float4 ca1 = *(const float4*)(coef + (size_t)(k + 1) * NHEADS);
    float4 cb1 = *(const float4*)(coef + (size_t)(k + 1) * NHEADS + 4);
    float2 p0 = bfpair(r0.x), p1 = bfpair(r0.y), p2 = bfpair(r0.z), p3 = bfpair(r0.w);
    float2 q0 = bfpair(r1.x), q1 = bfpair(r1.y), q2 = bfpair(r1.z), q3 = bfpair(r1.w);
    acc[0] += ca0.x * p0.x + ca1.x * q0.x;
    acc[1] += ca0.y * p0.y + ca1.y * q0.y;
    acc[2] += ca0.z * p1.x + ca1.z * q1.x;
    acc[3] += ca0.w * p1.y + ca1.w * q1.y;
    acc[4] += cb0.x * p2.x + cb1.x * q2.x;
    acc[5] += cb0.y * p2.y + cb1.y * q2.y;
    acc[6] += cb0.z * p3.x + cb1.z * q3.x;
    acc[7] += cb0.w * p3.y + cb1.w * q3.y;
  }
  if (k < end) {
    int s0 = nbr[k];
    uint4 r0 = *(const uint4*)(h2 + (size_t)s0 * (NHEADS * NCLASS) + (lane << 3));
    float4 ca0 = *(const float4*)(coef + (size_t)k * NHEADS);
    float4 cb0 = *(const float4*)(coef + (size_t)k * NHEADS + 4);
    float2 p0 = bfpair(r0.x), p1 = bfpair(r0.y), p2 = bfpair(r0.z), p3 = bfpair(r0.w);
    acc[0] += ca0.x * p0.x;
    acc[1] += ca0.y * p0.y;
    acc[2] += ca0.z * p1.x;
    acc[3] += ca0.w * p1.y;
    acc[4] += cb0.x * p2.x;
    acc[5] += cb0.y * p2.y;
    acc[6] += cb0.z * p3.x;
    acc[7] += cb0.w * p3.y;
  }
  float val = 0.f;
  #pragma unroll
  for (int h = 0; h < 8; h++) val += acc[h];
  val = val * 0.125f + b2[lane];
  float mx = val;
  #pragma unroll
  for (int o = 32; o > 0; o >>= 1) mx = fmaxf(mx, __shfl_xor(mx, o));
  float ex = __expf(val - mx);
  float sm = ex;
  #pragma unroll
  for (int o = 32; o > 0; o >>= 1) sm += __shfl_xor(sm, o);
  out[(size_t)node * NCLASS + lane] = val - mx - __logf(sm);
}

// ---------------- launch ----------------
extern "C" void kernel_launch(void* const* d_in, const int* in_sizes, int n_in,
                              void* d_out, int out_size, void* d_ws, size_t ws_size,
                              hipStream_t stream) {
  const float* x   = (const float*)d_in[0];
  const int* eidx  = (const int*)d_in[1];
  const float* W1  = (const float*)d_in[2];
  const float* a1s = (const float*)d_in[3];
  const float* a1d = (const float*)d_in[4];
  const float* b1  = (const float*)d_in[5];
  const float* W2  = (const float*)d_in[6];
  const float* a2s = (const float*)d_in[7];
  const float* a2d = (const float*)d_in[8];
  const float* b2  = (const float*)d_in[9];
  const int E0 = in_sizes[1] / 2;
  const int* esrc = eidx;
  const int* edst = eidx + E0;
  const int E = E0 + NN;

  char* w = (char*)d_ws;
  auto carve = [&](size_t bytes) {
    void* p = (void*)w;
    w += (bytes + 255) & ~(size_t)255;
    return p;
  };
  int* deg      = (int*)carve((size_t)NN * 4);
  int* offs     = (int*)carve((size_t)(NN + 1) * 4);
  int* cursor   = (int*)carve((size_t)NN * 4);
  int* nbr      = (int*)carve((size_t)E * 4);
  float* es1    = (float*)carve((size_t)NN * NHEADS * 4);
  float* ed1    = (float*)carve((size_t)NN * NHEADS * 4);
  float* coef   = (float*)carve((size_t)E * NHEADS * 4);
  unsigned short* xbf   = (unsigned short*)carve((size_t)NN * NF * 2);
  unsigned short* W1t   = (unsigned short*)carve((size_t)NF * NHID * 2);
  unsigned short* W2t   = (unsigned short*)carve((size_t)NHID * NHEADS * NCLASS * 2);
  unsigned short* h1b   = (unsigned short*)carve((size_t)NN * NHID * 2);
  unsigned short* out1b = (unsigned short*)carve((size_t)NN * NHID * 2);
  unsigned short* h2b   = (unsigned short*)carve((size_t)NN * NHEADS * NCLASS * 2);

  // CSR build
  k_init_deg<<<(NN + 255) / 256, 256, 0, stream>>>(deg);
  k_count<<<(E0 + 255) / 256, 256, 0, stream>>>(edst, E0, deg);
  k_scan<<<1, 1024, 0, stream>>>(deg, offs, cursor);
  k_scatter<<<(E0 + NN + 255) / 256, 256, 0, stream>>>(esrc, edst, E0, cursor, nbr);

  // casts
  k_cast4<<<(NN * NF / 4 + 255) / 256, 256, 0, stream>>>(x, xbf, NN * NF / 4);
  k_castWt<<<(NF * NHID + 255) / 256, 256, 0, stream>>>(W1, W1t, NF, NHID);
  k_castWt_perm<<<(NHID * NHEADS * NCLASS + 255) / 256, 256, 0, stream>>>(W2, W2t, NHID);

  // layer 1:  h1 = x @ W1  (50000x512 @ 512x256), bf16 out
  k_gemm_bf<<<dim3((NN / 16 + 3) / 4, NHID / 64), 256, 0, stream>>>(xbf, W1t, h1b,
                                                                    NN / 16, NF, NHID);
  k_escore_c<32><<<(NN * NHEADS + 255) / 256, 256, 0, stream>>>(h1b, a1s, a1d, es1, ed1);
  k_coef<<<(NN + 3) / 4, 256, 0, stream>>>(offs, nbr, es1, ed1, coef);
  k_agg1<<<(NN + 3) / 4, 256, 0, stream>>>(offs, nbr, h1b, coef, b1, out1b);

  // layer 2:  h2 = out1 @ W2  (50000x256 @ 256x512), permuted cols, bf16 out
  k_gemm_bf<<<dim3((NN / 16 + 3) / 4, (NHEADS * NCLASS) / 64), 256, 0, stream>>>(
      out1b, W2t, h2b, NN / 16, NHID, NHEADS * NCLASS);
  k_escore_p<<<(NN * NHEADS + 255) / 256, 256, 0, stream>>>(h2b, a2s, a2d, es1, ed1);
  k_coef<<<(NN + 3) / 4, 256, 0, stream>>>(offs, nbr, es1, ed1, coef);
  k_agg2<<<(NN + 3) / 4, 256, 0, stream>>>(offs, nbr, h2b, coef, b2, (float*)d_out);
}

// Round 5
// 678.189 us; speedup vs baseline: 1.7549x; 1.2151x over previous
//
#include <hip/hip_runtime.h>
#include <math.h>

#define NN 50000
#define NF 512
#define NHID 256
#define NCLASS 64
#define NHEADS 8

typedef __attribute__((ext_vector_type(8))) short bf16x8;
typedef __attribute__((ext_vector_type(4))) float f32x4;

static __device__ __forceinline__ unsigned short f2bf(float f) {
  unsigned int u = __float_as_uint(f);
  unsigned int r = (u + 0x7fffu + ((u >> 16) & 1u)) >> 16;
  return (unsigned short)r;
}
static __device__ __forceinline__ float bf2f(unsigned short u) {
  return __uint_as_float(((unsigned int)u) << 16);
}
static __device__ __forceinline__ float2 bfpair(unsigned int u) {
  return make_float2(__uint_as_float(u << 16), __uint_as_float(u & 0xffff0000u));
}

// ---------------- CSR build ----------------
__global__ void k_init_deg(int* deg) {
  int i = blockIdx.x * blockDim.x + threadIdx.x;
  if (i < NN) deg[i] = 1;  // self loop
}

__global__ void k_count(const int* __restrict__ dst, int E0, int* deg) {
  int i = blockIdx.x * blockDim.x + threadIdx.x;
  if (i < E0) atomicAdd(&deg[dst[i]], 1);
}

__global__ __launch_bounds__(1024) void k_scan(const int* __restrict__ deg, int* offs,
                                               int* cursor) {
  __shared__ int wbase[16];
  __shared__ int srun;
  int tid = threadIdx.x;
  int lane = tid & 63;
  int wv = tid >> 6;
  if (tid == 0) srun = 0;
  __syncthreads();
  for (int base = 0; base < NN; base += 1024) {
    int i = base + tid;
    int v = (i < NN) ? deg[i] : 0;
    int s = v;
    #pragma unroll
    for (int o = 1; o < 64; o <<= 1) {
      int t = __shfl_up(s, o);
      if (lane >= o) s += t;
    }
    if (lane == 63) wbase[wv] = s;
    __syncthreads();
    if (tid == 0) {
      int run = srun;
      #pragma unroll
      for (int w2 = 0; w2 < 16; w2++) {
        int t = wbase[w2];
        wbase[w2] = run;
        run += t;
      }
      srun = run;
    }
    __syncthreads();
    if (i < NN) {
      int e = wbase[wv] + s - v;  // exclusive
      offs[i] = e;
      cursor[i] = e;
    }
  }
  __syncthreads();
  if (tid == 0) offs[NN] = srun;
}

__global__ void k_scatter(const int* __restrict__ src, const int* __restrict__ dst,
                          int E0, int* cursor, int* __restrict__ nbr) {
  int i = blockIdx.x * blockDim.x + threadIdx.x;
  if (i < E0) {
    int pos = atomicAdd(&cursor[dst[i]], 1);
    nbr[pos] = src[i];
  } else if (i < E0 + NN) {
    int v = i - E0;
    int pos = atomicAdd(&cursor[v], 1);
    nbr[pos] = v;
  }
}

// ---------------- casts ----------------
__global__ void k_cast4(const float* __restrict__ in, unsigned short* __restrict__ out,
                        int n4) {
  int i = blockIdx.x * blockDim.x + threadIdx.x;
  if (i >= n4) return;
  float4 v = *(const float4*)(in + (size_t)i * 4);
  ushort4 o;
  o.x = f2bf(v.x); o.y = f2bf(v.y); o.z = f2bf(v.z); o.w = f2bf(v.w);
  *(ushort4*)(out + (size_t)i * 4) = o;
}

// W1 [K, cols] fp32 -> Wt [cols, K] bf16 (plain transpose)
__global__ void k_castWt(const float* __restrict__ W, unsigned short* __restrict__ Wt,
                         int K, int cols) {
  int i = blockIdx.x * blockDim.x + threadIdx.x;
  if (i >= K * cols) return;
  int k = i / cols, c = i % cols;
  Wt[(size_t)c * K + k] = f2bf(W[i]);
}

// W2 [K, h, c] fp32 -> Wt [c*8+h, K] bf16 (transpose + head/class permute)
__global__ void k_castWt_perm(const float* __restrict__ W, unsigned short* __restrict__ Wt,
                              int K) {
  int i = blockIdx.x * blockDim.x + threadIdx.x;
  if (i >= K * NHEADS * NCLASS) return;
  int k = i / (NHEADS * NCLASS);
  int rem = i % (NHEADS * NCLASS);
  int h = rem / NCLASS, c = rem % NCLASS;
  Wt[(size_t)(c * NHEADS + h) * K + k] = f2bf(W[i]);
}

// ---------------- bf16 MFMA GEMM, LDS-staged B, bf16 output ----------------
// A [rows,K] bf16, Bt [cols,K] bf16, C [rows,cols] bf16.
// Block: 64 rows x 256 cols (grid.y covers cols/256). Wave: 16 rows x 256 cols.
// B-tile [256 cols][32 k] staged in LDS, col stride 80 B (2-way banks = free).
__global__ __launch_bounds__(256) void k_gemm_bf(const unsigned short* __restrict__ A,
                                                 const unsigned short* __restrict__ Bt,
                                                 unsigned short* __restrict__ C,
                                                 int rows, int K, int cols) {
  __shared__ unsigned short Bs[256 * 40];  // 256 cols * 80 B = 20 KB
  int t = threadIdx.x;
  int wave = t >> 6, lane = t & 63;
  int quad = lane >> 4, sixt = lane & 15;
  int rb = blockIdx.x * 64 + wave * 16;
  int cb = blockIdx.y * 256;
  int arow = rb + sixt;
  const unsigned short* Ap = A + (size_t)(arow < rows ? arow : 0) * K + quad * 8;
  // staging addresses: chunk i = t + j*256; col = i>>2, kc = i&3
  const unsigned short* Bg = Bt + (size_t)(cb + (t >> 2)) * K + (t & 3) * 8;
  const size_t BgStep = (size_t)64 * K;  // +256 chunks = +64 cols
  char* BsW = (char*)Bs + (t >> 2) * 80 + (t & 3) * 16;
  f32x4 acc[16] = {};
  for (int k0 = 0; k0 < K; k0 += 32) {
    uint4 v0 = *(const uint4*)(Bg + k0);
    uint4 v1 = *(const uint4*)(Bg + BgStep + k0);
    uint4 v2 = *(const uint4*)(Bg + 2 * BgStep + k0);
    uint4 v3 = *(const uint4*)(Bg + 3 * BgStep + k0);
    bf16x8 a = *(const bf16x8*)(Ap + k0);
    *(uint4*)(BsW) = v0;
    *(uint4*)(BsW + 64 * 80) = v1;
    *(uint4*)(BsW + 128 * 80) = v2;
    *(uint4*)(BsW + 192 * 80) = v3;
    __syncthreads();
    #pragma unroll
    for (int g = 0; g < 16; g++) {
      bf16x8 b = *(const bf16x8*)((const char*)Bs + (g * 16 + sixt) * 80 + quad * 16);
      acc[g] = __builtin_amdgcn_mfma_f32_16x16x32_bf16(a, b, acc[g], 0, 0, 0);
    }
    __syncthreads();
  }
  #pragma unroll
  for (int r = 0; r < 4; r++) {
    int row = rb + quad * 4 + r;
    if (row < rows) {
      unsigned short* out = C + (size_t)row * cols + cb + sixt;
      #pragma unroll
      for (int g = 0; g < 16; g++) out[g * 16] = f2bf(acc[g][r]);
    }
  }
}

// ---------------- edge-score dots, contiguous layout (layer 1) ----------------
template <int C>
__global__ void k_escore_c(const unsigned short* __restrict__ h,
                           const float* __restrict__ asr, const float* __restrict__ ads,
                           float* __restrict__ es, float* __restrict__ ed) {
  int idx = blockIdx.x * blockDim.x + threadIdx.x;  // n*8 + head
  if (idx >= NN * NHEADS) return;
  int hd = idx & 7;
  const unsigned short* row = h + (size_t)idx * C;
  float s = 0.f, d = 0.f;
  #pragma unroll
  for (int c8 = 0; c8 < C / 8; c8++) {
    uint4 raw = *(const uint4*)(row + c8 * 8);
    float2 p0 = bfpair(raw.x), p1 = bfpair(raw.y), p2 = bfpair(raw.z), p3 = bfpair(raw.w);
    const float* as_ = asr + hd * C + c8 * 8;
    const float* ad_ = ads + hd * C + c8 * 8;
    s += p0.x * as_[0] + p0.y * as_[1] + p1.x * as_[2] + p1.y * as_[3] +
         p2.x * as_[4] + p2.y * as_[5] + p3.x * as_[6] + p3.y * as_[7];
    d += p0.x * ad_[0] + p0.y * ad_[1] + p1.x * ad_[2] + p1.y * ad_[3] +
         p2.x * ad_[4] + p2.y * ad_[5] + p3.x * ad_[6] + p3.y * ad_[7];
  }
  es[idx] = s;
  ed[idx] = d;
}

// ---------------- edge-score dots, permuted layout (layer 2) ----------------
__global__ void k_escore_p(const unsigned short* __restrict__ h,
                           const float* __restrict__ asr, const float* __restrict__ ads,
                           float* __restrict__ es, float* __restrict__ ed) {
  int idx = blockIdx.x * blockDim.x + threadIdx.x;  // n*8 + head
  if (idx >= NN * NHEADS) return;
  int hd = idx & 7;
  int n = idx >> 3;
  const unsigned short* row = h + (size_t)n * (NHEADS * NCLASS) + hd;
  float s = 0.f, d = 0.f;
  #pragma unroll
  for (int c = 0; c < NCLASS; c++) {
    float v = bf2f(row[c * NHEADS]);
    s += v * asr[hd * NCLASS + c];
    d += v * ads[hd * NCLASS + c];
  }
  es[idx] = s;
  ed[idx] = d;
}

// ---------------- per-edge softmax coefficients ----------------
__global__ __launch_bounds__(256) void k_coef(const int* __restrict__ offs,
                                              const int* __restrict__ nbr,
                                              const float* __restrict__ es,
                                              const float* __restrict__ ed,
                                              float* __restrict__ coef) {
  int node = blockIdx.x * 4 + (threadIdx.x >> 6);
  if (node >= NN) return;
  int lane = threadIdx.x & 63;
  int h = lane & 7;
  int sub = lane >> 3;
  int beg = offs[node], end = offs[node + 1];
  float edst = ed[node * NHEADS + h];
  float m = -1e30f, z = 0.f;
  for (int k = beg + sub; k < end; k += 8) {
    int s = nbr[k];
    float a = es[s * NHEADS + h] + edst;
    a = (a > 0.f) ? a : 0.2f * a;
    float mn = fmaxf(m, a);
    z = z * __expf(m - mn) + __expf(a - mn);
    m = mn;
  }
  #pragma unroll
  for (int o = 8; o < 64; o <<= 1) {
    float m2 = __shfl_xor(m, o);
    float z2 = __shfl_xor(z, o);
    float mn = fmaxf(m, m2);
    z = z * __expf(m - mn) + z2 * __expf(m2 - mn);
    m = mn;
  }
  float inv = 1.f / z;
  for (int k = beg + sub; k < end; k += 8) {
    int s = nbr[k];
    float a = es[s * NHEADS + h] + edst;
    a = (a > 0.f) ? a : 0.2f * a;
    coef[(size_t)k * NHEADS + h] = __expf(a - m) * inv;
  }
}

// ---------------- layer-1 aggregation: bf16 gather -> bf16 out ----------------
__global__ __launch_bounds__(256) void k_agg1(const int* __restrict__ offs,
                                              const int* __restrict__ nbr,
                                              const unsigned short* __restrict__ h1,
                                              const float* __restrict__ coef,
                                              const float* __restrict__ b1,
                                              unsigned short* __restrict__ out) {
  int node = blockIdx.x * 4 + (threadIdx.x >> 6);
  if (node >= NN) return;
  int lane = threadIdx.x & 63;
  int head = lane >> 3;
  int beg = offs[node], end = offs[node + 1];
  float4 acc = make_float4(0.f, 0.f, 0.f, 0.f);
  int k = beg;
  for (; k + 1 < end; k += 2) {
    int s0 = nbr[k], s1 = nbr[k + 1];
    float c0 = coef[(size_t)k * NHEADS + head];
    float c1 = coef[(size_t)(k + 1) * NHEADS + head];
    uint2 r0 = *(const uint2*)(h1 + (size_t)s0 * NHID + (lane << 2));
    uint2 r1 = *(const uint2*)(h1 + (size_t)s1 * NHID + (lane << 2));
    float2 a0 = bfpair(r0.x), a1 = bfpair(r0.y);
    float2 b0 = bfpair(r1.x), b1_ = bfpair(r1.y);
    acc.x += c0 * a0.x + c1 * b0.x;
    acc.y += c0 * a0.y + c1 * b0.y;
    acc.z += c0 * a1.x + c1 * b1_.x;
    acc.w += c0 * a1.y + c1 * b1_.y;
  }
  if (k < end) {
    int s0 = nbr[k];
    float c0 = coef[(size_t)k * NHEADS + head];
    uint2 r0 = *(const uint2*)(h1 + (size_t)s0 * NHID + (lane << 2));
    float2 a0 = bfpair(r0.x), a1 = bfpair(r0.y);
    acc.x += c0 * a0.x;
    acc.y += c0 * a0.y;
    acc.z += c0 * a1.x;
    acc.w += c0 * a1.y;
  }
  int col = lane << 2;
  ushort4 o;
  o.x = f2bf(fmaxf(acc.x + b1[col + 0], 0.f));
  o.y = f2bf(fmaxf(acc.y + b1[col + 1], 0.f));
  o.z = f2bf(fmaxf(acc.z + b1[col + 2], 0.f));
  o.w = f2bf(fmaxf(acc.w + b1[col + 3], 0.f));
  *(ushort4*)(out + (size_t)node * NHID + col) = o;
}

// ---------------- layer-2 aggregation + head-mean + bias + log_softmax ----------------
__global__ __launch_bounds__(256) void k_agg2(const int* __restrict__ offs,
                                              const int* __restrict__ nbr,
                                              const unsigned short* __restrict__ h2,
                                              const float* __restrict__ coef,
                                              const float* __restrict__ b2,
                                              float* __restrict__ out) {
  int node = blockIdx.x * 4 + (threadIdx.x >> 6);
  if (node >= NN) return;
  int lane = threadIdx.x & 63;  // class index
  float acc[8] = {};
  int beg = offs[node], end = offs[node + 1];
  int k = beg;
  for (; k + 1 < end; k += 2) {
    int s0 = nbr[k], s1 = nbr[k + 1];
    uint4 r0 = *(const uint4*)(h2 + (size_t)s0 * (NHEADS * NCLASS) + (lane << 3));
    uint4 r1 = *(const uint4*)(h2 + (size_t)s1 * (NHEADS * NCLASS) + (lane << 3));
    float4 ca0 = *(const float4*)(coef + (size_t)k * NHEADS);
    float4 cb0 = *(const float4*)(coef + (size_t)k * NHEADS + 4);
    float4 ca1 = *(const float4*)(coef + (size_t)(k + 1) * NHEADS);
    float4 cb1 = *(const float4*)(coef + (size_t)(k + 1) * NHEADS + 4);
    float2 p0 = bfpair(r0.x), p1 = bfpair(r0.y), p2 = bfpair(r0.z), p3 = bfpair(r0.w);
    float2 q0 = bfpair(r1.x), q1 = bfpair(r1.y), q2 = bfpair(r1.z), q3 = bfpair(r1.w);
    acc[0] += ca0.x * p0.x + ca1.x * q0.x;
    acc[1] += ca0.y * p0.y + ca1.y * q0.y;
    acc[2] += ca0.z * p1.x + ca1.z * q1.x;
    acc[3] += ca0.w * p1.y + ca1.w * q1.y;
    acc[4] += cb0.x * p2.x + cb1.x * q2.x;
    acc[5] += cb0.y * p2.y + cb1.y * q2.y;
    acc[6] += cb0.z * p3.x + cb1.z * q3.x;
    acc[7] += cb0.w * p3.y + cb1.w * q3.y;
  }
  if (k < end) {
    int s0 = nbr[k];
    uint4 r0 = *(const uint4*)(h2 + (size_t)s0 * (NHEADS * NCLASS) + (lane << 3));
    float4 ca0 = *(const float4*)(coef + (size_t)k * NHEADS);
    float4 cb0 = *(const float4*)(coef + (size_t)k * NHEADS + 4);
    float2 p0 = bfpair(r0.x), p1 = bfpair(r0.y), p2 = bfpair(r0.z), p3 = bfpair(r0.w);
    acc[0] += ca0.x * p0.x;
    acc[1] += ca0.y * p0.y;
    acc[2] += ca0.z * p1.x;
    acc[3] += ca0.w * p1.y;
    acc[4] += cb0.x * p2.x;
    acc[5] += cb0.y * p2.y;
    acc[6] += cb0.z * p3.x;
    acc[7] += cb0.w * p3.y;
  }
  float val = 0.f;
  #pragma unroll
  for (int h = 0; h < 8; h++) val += acc[h];
  val = val * 0.125f + b2[lane];
  float mx = val;
  #pragma unroll
  for (int o = 32; o > 0; o >>= 1) mx = fmaxf(mx, __shfl_xor(mx, o));
  float ex = __expf(val - mx);
  float sm = ex;
  #pragma unroll
  for (int o = 32; o > 0; o >>= 1) sm += __shfl_xor(sm, o);
  out[(size_t)node * NCLASS + lane] = val - mx - __logf(sm);
}

// ---------------- launch ----------------
extern "C" void kernel_launch(void* const* d_in, const int* in_sizes, int n_in,
                              void* d_out, int out_size, void* d_ws, size_t ws_size,
                              hipStream_t stream) {
  const float* x   = (const float*)d_in[0];
  const int* eidx  = (const int*)d_in[1];
  const float* W1  = (const float*)d_in[2];
  const float* a1s = (const float*)d_in[3];
  const float* a1d = (const float*)d_in[4];
  const float* b1  = (const float*)d_in[5];
  const float* W2  = (const float*)d_in[6];
  const float* a2s = (const float*)d_in[7];
  const float* a2d = (const float*)d_in[8];
  const float* b2  = (const float*)d_in[9];
  const int E0 = in_sizes[1] / 2;
  const int* esrc = eidx;
  const int* edst = eidx + E0;
  const int E = E0 + NN;

  char* w = (char*)d_ws;
  auto carve = [&](size_t bytes) {
    void* p = (void*)w;
    w += (bytes + 255) & ~(size_t)255;
    return p;
  };
  int* deg      = (int*)carve((size_t)NN * 4);
  int* offs     = (int*)carve((size_t)(NN + 1) * 4);
  int* cursor   = (int*)carve((size_t)NN * 4);
  int* nbr      = (int*)carve((size_t)E * 4);
  float* es1    = (float*)carve((size_t)NN * NHEADS * 4);
  float* ed1    = (float*)carve((size_t)NN * NHEADS * 4);
  float* coef   = (float*)carve((size_t)E * NHEADS * 4);
  unsigned short* xbf   = (unsigned short*)carve((size_t)NN * NF * 2);
  unsigned short* W1t   = (unsigned short*)carve((size_t)NF * NHID * 2);
  unsigned short* W2t   = (unsigned short*)carve((size_t)NHID * NHEADS * NCLASS * 2);
  unsigned short* h1b   = (unsigned short*)carve((size_t)NN * NHID * 2);
  unsigned short* out1b = (unsigned short*)carve((size_t)NN * NHID * 2);
  unsigned short* h2b   = (unsigned short*)carve((size_t)NN * NHEADS * NCLASS * 2);

  // CSR build
  k_init_deg<<<(NN + 255) / 256, 256, 0, stream>>>(deg);
  k_count<<<(E0 + 255) / 256, 256, 0, stream>>>(edst, E0, deg);
  k_scan<<<1, 1024, 0, stream>>>(deg, offs, cursor);
  k_scatter<<<(E0 + NN + 255) / 256, 256, 0, stream>>>(esrc, edst, E0, cursor, nbr);

  // casts
  k_cast4<<<(NN * NF / 4 + 255) / 256, 256, 0, stream>>>(x, xbf, NN * NF / 4);
  k_castWt<<<(NF * NHID + 255) / 256, 256, 0, stream>>>(W1, W1t, NF, NHID);
  k_castWt_perm<<<(NHID * NHEADS * NCLASS + 255) / 256, 256, 0, stream>>>(W2, W2t, NHID);

  // layer 1:  h1 = x @ W1  (50000x512 @ 512x256), bf16 out
  k_gemm_bf<<<dim3((NN + 63) / 64, NHID / 256), 256, 0, stream>>>(xbf, W1t, h1b,
                                                                  NN, NF, NHID);
  k_escore_c<32><<<(NN * NHEADS + 255) / 256, 256, 0, stream>>>(h1b, a1s, a1d, es1, ed1);
  k_coef<<<(NN + 3) / 4, 256, 0, stream>>>(offs, nbr, es1, ed1, coef);
  k_agg1<<<(NN + 3) / 4, 256, 0, stream>>>(offs, nbr, h1b, coef, b1, out1b);

  // layer 2:  h2 = out1 @ W2  (50000x256 @ 256x512), permuted cols, bf16 out
  k_gemm_bf<<<dim3((NN + 63) / 64, (NHEADS * NCLASS) / 256), 256, 0, stream>>>(
      out1b, W2t, h2b, NN, NHID, NHEADS * NCLASS);
  k_escore_p<<<(NN * NHEADS + 255) / 256, 256, 0, stream>>>(h2b, a2s, a2d, es1, ed1);
  k_coef<<<(NN + 3) / 4, 256, 0, stream>>>(offs, nbr, es1, ed1, coef);
  k_agg2<<<(NN + 3) / 4, 256, 0, stream>>>(offs, nbr, h2b, coef, b2, (float*)d_out);
}

// Round 6
// 677.932 us; speedup vs baseline: 1.7556x; 1.0004x over previous
//
#include <hip/hip_runtime.h>
#include <math.h>

#define NN 50000
#define NF 512
#define NHID 256
#define NCLASS 64
#define NHEADS 8

typedef __attribute__((ext_vector_type(8))) short bf16x8;
typedef __attribute__((ext_vector_type(4))) float f32x4;

static __device__ __forceinline__ unsigned short f2bf(float f) {
  unsigned int u = __float_as_uint(f);
  unsigned int r = (u + 0x7fffu + ((u >> 16) & 1u)) >> 16;
  return (unsigned short)r;
}
static __device__ __forceinline__ float bf2f(unsigned short u) {
  return __uint_as_float(((unsigned int)u) << 16);
}
static __device__ __forceinline__ float2 bfpair(unsigned int u) {
  return make_float2(__uint_as_float(u << 16), __uint_as_float(u & 0xffff0000u));
}

// ---------------- CSR build ----------------
__global__ void k_init_deg(int* deg) {
  int i = blockIdx.x * blockDim.x + threadIdx.x;
  if (i < NN) deg[i] = 1;  // self loop
}

__global__ void k_count(const int* __restrict__ dst, int E0, int* deg) {
  int i = blockIdx.x * blockDim.x + threadIdx.x;
  if (i < E0) atomicAdd(&deg[dst[i]], 1);
}

// 4 elements per thread: 13 chunks of 4096 instead of 50 chunks of 1024
__global__ __launch_bounds__(1024) void k_scan(const int* __restrict__ deg, int* offs,
                                               int* cursor) {
  __shared__ int wbase[16];
  __shared__ int srun;
  int tid = threadIdx.x;
  int lane = tid & 63;
  int wv = tid >> 6;
  if (tid == 0) srun = 0;
  __syncthreads();
  for (int base = 0; base < NN; base += 4096) {
    int i = base + tid * 4;
    int4 v;
    if (i + 3 < NN) {
      v = *(const int4*)(deg + i);
    } else {
      v.x = (i + 0 < NN) ? deg[i + 0] : 0;
      v.y = (i + 1 < NN) ? deg[i + 1] : 0;
      v.z = (i + 2 < NN) ? deg[i + 2] : 0;
      v.w = (i + 3 < NN) ? deg[i + 3] : 0;
    }
    int tot = v.x + v.y + v.z + v.w;
    int s = tot;
    #pragma unroll
    for (int o = 1; o < 64; o <<= 1) {
      int t = __shfl_up(s, o);
      if (lane >= o) s += t;
    }
    if (lane == 63) wbase[wv] = s;
    __syncthreads();
    if (tid == 0) {
      int run = srun;
      #pragma unroll
      for (int w2 = 0; w2 < 16; w2++) {
        int t = wbase[w2];
        wbase[w2] = run;
        run += t;
      }
      srun = run;
    }
    __syncthreads();
    int p = wbase[wv] + s - tot;  // exclusive prefix for element i
    if (i + 0 < NN) { offs[i + 0] = p; cursor[i + 0] = p; p += v.x; }
    if (i + 1 < NN) { offs[i + 1] = p; cursor[i + 1] = p; p += v.y; }
    if (i + 2 < NN) { offs[i + 2] = p; cursor[i + 2] = p; p += v.z; }
    if (i + 3 < NN) { offs[i + 3] = p; cursor[i + 3] = p; }
  }
  __syncthreads();
  if (tid == 0) offs[NN] = srun;
}

__global__ void k_scatter(const int* __restrict__ src, const int* __restrict__ dst,
                          int E0, int* cursor, int* __restrict__ nbr) {
  int i = blockIdx.x * blockDim.x + threadIdx.x;
  if (i < E0) {
    int pos = atomicAdd(&cursor[dst[i]], 1);
    nbr[pos] = src[i];
  } else if (i < E0 + NN) {
    int v = i - E0;
    int pos = atomicAdd(&cursor[v], 1);
    nbr[pos] = v;
  }
}

// ---------------- casts ----------------
__global__ void k_cast4(const float* __restrict__ in, unsigned short* __restrict__ out,
                        int n4) {
  int i = blockIdx.x * blockDim.x + threadIdx.x;
  if (i >= n4) return;
  float4 v = *(const float4*)(in + (size_t)i * 4);
  ushort4 o;
  o.x = f2bf(v.x); o.y = f2bf(v.y); o.z = f2bf(v.z); o.w = f2bf(v.w);
  *(ushort4*)(out + (size_t)i * 4) = o;
}

// W1 [K, cols] fp32 -> Wt [cols, K] bf16 (plain transpose)
__global__ void k_castWt(const float* __restrict__ W, unsigned short* __restrict__ Wt,
                         int K, int cols) {
  int i = blockIdx.x * blockDim.x + threadIdx.x;
  if (i >= K * cols) return;
  int k = i / cols, c = i % cols;
  Wt[(size_t)c * K + k] = f2bf(W[i]);
}

// W2 [K, h, c] fp32 -> Wt [c*8+h, K] bf16 (transpose + head/class permute)
__global__ void k_castWt_perm(const float* __restrict__ W, unsigned short* __restrict__ Wt,
                              int K) {
  int i = blockIdx.x * blockDim.x + threadIdx.x;
  if (i >= K * NHEADS * NCLASS) return;
  int k = i / (NHEADS * NCLASS);
  int rem = i % (NHEADS * NCLASS);
  int h = rem / NCLASS, c = rem % NCLASS;
  Wt[(size_t)(c * NHEADS + h) * K + k] = f2bf(W[i]);
}

// ---------------- bf16 MFMA GEMM, LDS-staged B, bf16 output ----------------
// Block: 64 rows x 256 cols. Wave: 32 rows x 128 cols (2 A-frags x 8 B-frags per
// 16 MFMAs -> half the ds_read traffic of a 16x256 wave).
// B-tile [256 cols][32 k] in LDS, col stride 80 B (2-way banks = free).
__global__ __launch_bounds__(256) void k_gemm_bf(const unsigned short* __restrict__ A,
                                                 const unsigned short* __restrict__ Bt,
                                                 unsigned short* __restrict__ C,
                                                 int rows, int K, int cols) {
  __shared__ unsigned short Bs[256 * 40];  // 20 KB
  int t = threadIdx.x;
  int wave = t >> 6, lane = t & 63;
  int quad = lane >> 4, sixt = lane & 15;
  int rb = blockIdx.x * 64 + (wave >> 1) * 32;
  int cw = (wave & 1) * 128;  // wave's col offset within the 256-tile
  int cbw = blockIdx.y * 256 + cw;
  int r0 = rb + sixt, r1 = rb + 16 + sixt;
  const unsigned short* Ap0 = A + (size_t)(r0 < rows ? r0 : 0) * K + quad * 8;
  const unsigned short* Ap1 = A + (size_t)(r1 < rows ? r1 : 0) * K + quad * 8;
  const unsigned short* Bg = Bt + (size_t)(blockIdx.y * 256 + (t >> 2)) * K + (t & 3) * 8;
  const size_t BgStep = (size_t)64 * K;
  char* BsW = (char*)Bs + (t >> 2) * 80 + (t & 3) * 16;
  f32x4 acc0[8] = {}, acc1[8] = {};
  for (int k0 = 0; k0 < K; k0 += 32) {
    uint4 v0 = *(const uint4*)(Bg + k0);
    uint4 v1 = *(const uint4*)(Bg + BgStep + k0);
    uint4 v2 = *(const uint4*)(Bg + 2 * BgStep + k0);
    uint4 v3 = *(const uint4*)(Bg + 3 * BgStep + k0);
    bf16x8 a0 = *(const bf16x8*)(Ap0 + k0);
    bf16x8 a1 = *(const bf16x8*)(Ap1 + k0);
    *(uint4*)(BsW) = v0;
    *(uint4*)(BsW + 64 * 80) = v1;
    *(uint4*)(BsW + 128 * 80) = v2;
    *(uint4*)(BsW + 192 * 80) = v3;
    __syncthreads();
    #pragma unroll
    for (int g = 0; g < 8; g++) {
      bf16x8 b = *(const bf16x8*)((const char*)Bs + (cw + g * 16 + sixt) * 80 + quad * 16);
      acc0[g] = __builtin_amdgcn_mfma_f32_16x16x32_bf16(a0, b, acc0[g], 0, 0, 0);
      acc1[g] = __builtin_amdgcn_mfma_f32_16x16x32_bf16(a1, b, acc1[g], 0, 0, 0);
    }
    __syncthreads();
  }
  #pragma unroll
  for (int r = 0; r < 4; r++) {
    int row = rb + quad * 4 + r;
    if (row < rows) {
      unsigned short* out = C + (size_t)row * cols + cbw + sixt;
      #pragma unroll
      for (int g = 0; g < 8; g++) out[g * 16] = f2bf(acc0[g][r]);
    }
    int row2 = row + 16;
    if (row2 < rows) {
      unsigned short* out = C + (size_t)row2 * cols + cbw + sixt;
      #pragma unroll
      for (int g = 0; g < 8; g++) out[g * 16] = f2bf(acc1[g][r]);
    }
  }
}

// ---------------- edge-score dots, contiguous layout (layer 1) ----------------
template <int C>
__global__ void k_escore_c(const unsigned short* __restrict__ h,
                           const float* __restrict__ asr, const float* __restrict__ ads,
                           float* __restrict__ es, float* __restrict__ ed) {
  int idx = blockIdx.x * blockDim.x + threadIdx.x;  // n*8 + head
  if (idx >= NN * NHEADS) return;
  int hd = idx & 7;
  const unsigned short* row = h + (size_t)idx * C;
  float s = 0.f, d = 0.f;
  #pragma unroll
  for (int c8 = 0; c8 < C / 8; c8++) {
    uint4 raw = *(const uint4*)(row + c8 * 8);
    float2 p0 = bfpair(raw.x), p1 = bfpair(raw.y), p2 = bfpair(raw.z), p3 = bfpair(raw.w);
    const float* as_ = asr + hd * C + c8 * 8;
    const float* ad_ = ads + hd * C + c8 * 8;
    s += p0.x * as_[0] + p0.y * as_[1] + p1.x * as_[2] + p1.y * as_[3] +
         p2.x * as_[4] + p2.y * as_[5] + p3.x * as_[6] + p3.y * as_[7];
    d += p0.x * ad_[0] + p0.y * ad_[1] + p1.x * ad_[2] + p1.y * ad_[3] +
         p2.x * ad_[4] + p2.y * ad_[5] + p3.x * ad_[6] + p3.y * ad_[7];
  }
  es[idx] = s;
  ed[idx] = d;
}

// ---------------- edge-score dots, permuted layout (layer 2) ----------------
__global__ void k_escore_p(const unsigned short* __restrict__ h,
                           const float* __restrict__ asr, const float* __restrict__ ads,
                           float* __restrict__ es, float* __restrict__ ed) {
  int idx = blockIdx.x * blockDim.x + threadIdx.x;  // n*8 + head
  if (idx >= NN * NHEADS) return;
  int hd = idx & 7;
  int n = idx >> 3;
  const unsigned short* row = h + (size_t)n * (NHEADS * NCLASS) + hd;
  float s = 0.f, d = 0.f;
  #pragma unroll
  for (int c = 0; c < NCLASS; c++) {
    float v = bf2f(row[c * NHEADS]);
    s += v * asr[hd * NCLASS + c];
    d += v * ads[hd * NCLASS + c];
  }
  es[idx] = s;
  ed[idx] = d;
}

// ---------------- per-edge softmax coefficients ----------------
// Sweep 1: gather es, compute alpha, store raw alpha into coef, online (m,z).
// Butterfly merge. Sweep 2: re-read coef COALESCED, rescale in place.
__global__ __launch_bounds__(256) void k_coef(const int* __restrict__ offs,
                                              const int* __restrict__ nbr,
                                              const float* __restrict__ es,
                                              const float* __restrict__ ed,
                                              float* __restrict__ coef) {
  int node = blockIdx.x * 4 + (threadIdx.x >> 6);
  if (node >= NN) return;
  int lane = threadIdx.x & 63;
  int h = lane & 7;
  int sub = lane >> 3;
  int beg = offs[node], end = offs[node + 1];
  float edst = ed[node * NHEADS + h];
  float m = -1e30f, z = 0.f;
  for (int k = beg + sub; k < end; k += 8) {
    int s = nbr[k];
    float a = es[s * NHEADS + h] + edst;
    a = (a > 0.f) ? a : 0.2f * a;
    coef[(size_t)k * NHEADS + h] = a;
    float mn = fmaxf(m, a);
    z = z * __expf(m - mn) + __expf(a - mn);
    m = mn;
  }
  #pragma unroll
  for (int o = 8; o < 64; o <<= 1) {
    float m2 = __shfl_xor(m, o);
    float z2 = __shfl_xor(z, o);
    float mn = fmaxf(m, m2);
    z = z * __expf(m - mn) + z2 * __expf(m2 - mn);
    m = mn;
  }
  float inv = 1.f / z;
  for (int k = beg + sub; k < end; k += 8) {
    size_t idx = (size_t)k * NHEADS + h;
    coef[idx] = __expf(coef[idx] - m) * inv;
  }
}

// ---------------- layer-1 aggregation: bf16 gather, 4-edge unroll ----------------
__global__ __launch_bounds__(256) void k_agg1(const int* __restrict__ offs,
                                              const int* __restrict__ nbr,
                                              const unsigned short* __restrict__ h1,
                                              const float* __restrict__ coef,
                                              const float* __restrict__ b1,
                                              unsigned short* __restrict__ out) {
  int node = blockIdx.x * 4 + (threadIdx.x >> 6);
  if (node >= NN) return;
  int lane = threadIdx.x & 63;
  int head = lane >> 3;
  int beg = offs[node], end = offs[node + 1];
  float4 acc = make_float4(0.f, 0.f, 0.f, 0.f);
  int k = beg;
  for (; k + 3 < end; k += 4) {
    int s0 = nbr[k], s1 = nbr[k + 1], s2 = nbr[k + 2], s3 = nbr[k + 3];
    float c0 = coef[(size_t)k * NHEADS + head];
    float c1 = coef[(size_t)(k + 1) * NHEADS + head];
    float c2 = coef[(size_t)(k + 2) * NHEADS + head];
    float c3 = coef[(size_t)(k + 3) * NHEADS + head];
    uint2 r0 = *(const uint2*)(h1 + (size_t)s0 * NHID + (lane << 2));
    uint2 r1 = *(const uint2*)(h1 + (size_t)s1 * NHID + (lane << 2));
    uint2 r2 = *(const uint2*)(h1 + (size_t)s2 * NHID + (lane << 2));
    uint2 r3 = *(const uint2*)(h1 + (size_t)s3 * NHID + (lane << 2));
    float2 a0 = bfpair(r0.x), a1 = bfpair(r0.y);
    float2 b0 = bfpair(r1.x), b1_ = bfpair(r1.y);
    float2 d0 = bfpair(r2.x), d1 = bfpair(r2.y);
    float2 e0 = bfpair(r3.x), e1 = bfpair(r3.y);
    acc.x += c0 * a0.x + c1 * b0.x + c2 * d0.x + c3 * e0.x;
    acc.y += c0 * a0.y + c1 * b0.y + c2 * d0.y + c3 * e0.y;
    acc.z += c0 * a1.x + c1 * b1_.x + c2 * d1.x + c3 * e1.x;
    acc.w += c0 * a1.y + c1 * b1_.y + c2 * d1.y + c3 * e1.y;
  }
  for (; k < end; k++) {
    int s0 = nbr[k];
    float c0 = coef[(size_t)k * NHEADS + head];
    uint2 r0 = *(const uint2*)(h1 + (size_t)s0 * NHID + (lane << 2));
    float2 a0 = bfpair(r0.x), a1 = bfpair(r0.y);
    acc.x += c0 * a0.x;
    acc.y += c0 * a0.y;
    acc.z += c0 * a1.x;
    acc.w += c0 * a1.y;
  }
  int col = lane << 2;
  ushort4 o;
  o.x = f2bf(fmaxf(acc.x + b1[col + 0], 0.f));
  o.y = f2bf(fmaxf(acc.y + b1[col + 1], 0.f));
  o.z = f2bf(fmaxf(acc.z + b1[col + 2], 0.f));
  o.w = f2bf(fmaxf(acc.w + b1[col + 3], 0.f));
  *(ushort4*)(out + (size_t)node * NHID + col) = o;
}

// ---------------- layer-2 aggregation + head-mean + bias + log_softmax ----------------
__global__ __launch_bounds__(256) void k_agg2(const int* __restrict__ offs,
                                              const int* __restrict__ nbr,
                                              const unsigned short* __restrict__ h2,
                                              const float* __restrict__ coef,
                                              const float* __restrict__ b2,
                                              float* __restrict__ out) {
  int node = blockIdx.x * 4 + (threadIdx.x >> 6);
  if (node >= NN) return;
  int lane = threadIdx.x & 63;  // class index
  float acc[8] = {};
  int beg = offs[node], end = offs[node + 1];
  int k = beg;
  for (; k + 3 < end; k += 4) {
    int s0 = nbr[k], s1 = nbr[k + 1], s2 = nbr[k + 2], s3 = nbr[k + 3];
    uint4 r0 = *(const uint4*)(h2 + (size_t)s0 * (NHEADS * NCLASS) + (lane << 3));
    uint4 r1 = *(const uint4*)(h2 + (size_t)s1 * (NHEADS * NCLASS) + (lane << 3));
    uint4 r2 = *(const uint4*)(h2 + (size_t)s2 * (NHEADS * NCLASS) + (lane << 3));
    uint4 r3 = *(const uint4*)(h2 + (size_t)s3 * (NHEADS * NCLASS) + (lane << 3));
    float4 ca0 = *(const float4*)(coef + (size_t)k * NHEADS);
    float4 cb0 = *(const float4*)(coef + (size_t)k * NHEADS + 4);
    float4 ca1 = *(const float4*)(coef + (size_t)(k + 1) * NHEADS);
    float4 cb1 = *(const float4*)(coef + (size_t)(k + 1) * NHEADS + 4);
    float4 ca2 = *(const float4*)(coef + (size_t)(k + 2) * NHEADS);
    float4 cb2 = *(const float4*)(coef + (size_t)(k + 2) * NHEADS + 4);
    float4 ca3 = *(const float4*)(coef + (size_t)(k + 3) * NHEADS);
    float4 cb3 = *(const float4*)(coef + (size_t)(k + 3) * NHEADS + 4);
    float2 p0 = bfpair(r0.x), p1 = bfpair(r0.y), p2 = bfpair(r0.z), p3 = bfpair(r0.w);
    float2 q0 = bfpair(r1.x), q1 = bfpair(r1.y), q2 = bfpair(r1.z), q3 = bfpair(r1.w);
    float2 u0 = bfpair(r2.x), u1 = bfpair(r2.y), u2 = bfpair(r2.z), u3 = bfpair(r2.w);
    float2 w0 = bfpair(r3.x), w1 = bfpair(r3.y), w2 = bfpair(r3.z), w3 = bfpair(r3.w);
    acc[0] += ca0.x * p0.x + ca1.x * q0.x + ca2.x * u0.x + ca3.x * w0.x;
    acc[1] += ca0.y * p0.y + ca1.y * q0.y + ca2.y * u0.y + ca3.y * w0.y;
    acc[2] += ca0.z * p1.x + ca1.z * q1.x + ca2.z * u1.x + ca3.z * w1.x;
    acc[3] += ca0.w * p1.y + ca1.w * q1.y + ca2.w * u1.y + ca3.w * w1.y;
    acc[4] += cb0.x * p2.x + cb1.x * q2.x + cb2.x * u2.x + cb3.x * w2.x;
    acc[5] += cb0.y * p2.y + cb1.y * q2.y + cb2.y * u2.y + cb3.y * w2.y;
    acc[6] += cb0.z * p3.x + cb1.z * q3.x + cb2.z * u3.x + cb3.z * w3.x;
    acc[7] += cb0.w * p3.y + cb1.w * q3.y + cb2.w * u3.y + cb3.w * w3.y;
  }
  for (; k < end; k++) {
    int s0 = nbr[k];
    uint4 r0 = *(const uint4*)(h2 + (size_t)s0 * (NHEADS * NCLASS) + (lane << 3));
    float4 ca0 = *(const float4*)(coef + (size_t)k * NHEADS);
    float4 cb0 = *(const float4*)(coef + (size_t)k * NHEADS + 4);
    float2 p0 = bfpair(r0.x), p1 = bfpair(r0.y), p2 = bfpair(r0.z), p3 = bfpair(r0.w);
    acc[0] += ca0.x * p0.x;
    acc[1] += ca0.y * p0.y;
    acc[2] += ca0.z * p1.x;
    acc[3] += ca0.w * p1.y;
    acc[4] += cb0.x * p2.x;
    acc[5] += cb0.y * p2.y;
    acc[6] += cb0.z * p3.x;
    acc[7] += cb0.w * p3.y;
  }
  float val = 0.f;
  #pragma unroll
  for (int h = 0; h < 8; h++) val += acc[h];
  val = val * 0.125f + b2[lane];
  float mx = val;
  #pragma unroll
  for (int o = 32; o > 0; o >>= 1) mx = fmaxf(mx, __shfl_xor(mx, o));
  float ex = __expf(val - mx);
  float sm = ex;
  #pragma unroll
  for (int o = 32; o > 0; o >>= 1) sm += __shfl_xor(sm, o);
  out[(size_t)node * NCLASS + lane] = val - mx - __logf(sm);
}

// ---------------- launch ----------------
extern "C" void kernel_launch(void* const* d_in, const int* in_sizes, int n_in,
                              void* d_out, int out_size, void* d_ws, size_t ws_size,
                              hipStream_t stream) {
  const float* x   = (const float*)d_in[0];
  const int* eidx  = (const int*)d_in[1];
  const float* W1  = (const float*)d_in[2];
  const float* a1s = (const float*)d_in[3];
  const float* a1d = (const float*)d_in[4];
  const float* b1  = (const float*)d_in[5];
  const float* W2  = (const float*)d_in[6];
  const float* a2s = (const float*)d_in[7];
  const float* a2d = (const float*)d_in[8];
  const float* b2  = (const float*)d_in[9];
  const int E0 = in_sizes[1] / 2;
  const int* esrc = eidx;
  const int* edst = eidx + E0;
  const int E = E0 + NN;

  char* w = (char*)d_ws;
  auto carve = [&](size_t bytes) {
    void* p = (void*)w;
    w += (bytes + 255) & ~(size_t)255;
    return p;
  };
  int* deg      = (int*)carve((size_t)NN * 4);
  int* offs     = (int*)carve((size_t)(NN + 1) * 4);
  int* cursor   = (int*)carve((size_t)NN * 4);
  int* nbr      = (int*)carve((size_t)E * 4);
  float* es1    = (float*)carve((size_t)NN * NHEADS * 4);
  float* ed1    = (float*)carve((size_t)NN * NHEADS * 4);
  float* coef   = (float*)carve((size_t)E * NHEADS * 4);
  unsigned short* xbf   = (unsigned short*)carve((size_t)NN * NF * 2);
  unsigned short* W1t   = (unsigned short*)carve((size_t)NF * NHID * 2);
  unsigned short* W2t   = (unsigned short*)carve((size_t)NHID * NHEADS * NCLASS * 2);
  unsigned short* h1b   = (unsigned short*)carve((size_t)NN * NHID * 2);
  unsigned short* out1b = (unsigned short*)carve((size_t)NN * NHID * 2);
  unsigned short* h2b   = (unsigned short*)carve((size_t)NN * NHEADS * NCLASS * 2);

  // CSR build
  k_init_deg<<<(NN + 255) / 256, 256, 0, stream>>>(deg);
  k_count<<<(E0 + 255) / 256, 256, 0, stream>>>(edst, E0, deg);
  k_scan<<<1, 1024, 0, stream>>>(deg, offs, cursor);
  k_scatter<<<(E0 + NN + 255) / 256, 256, 0, stream>>>(esrc, edst, E0, cursor, nbr);

  // casts
  k_cast4<<<(NN * NF / 4 + 255) / 256, 256, 0, stream>>>(x, xbf, NN * NF / 4);
  k_castWt<<<(NF * NHID + 255) / 256, 256, 0, stream>>>(W1, W1t, NF, NHID);
  k_castWt_perm<<<(NHID * NHEADS * NCLASS + 255) / 256, 256, 0, stream>>>(W2, W2t, NHID);

  // layer 1:  h1 = x @ W1  (50000x512 @ 512x256), bf16 out
  k_gemm_bf<<<dim3((NN + 63) / 64, NHID / 256), 256, 0, stream>>>(xbf, W1t, h1b,
                                                                  NN, NF, NHID);
  k_escore_c<32><<<(NN * NHEADS + 255) / 256, 256, 0, stream>>>(h1b, a1s, a1d, es1, ed1);
  k_coef<<<(NN + 3) / 4, 256, 0, stream>>>(offs, nbr, es1, ed1, coef);
  k_agg1<<<(NN + 3) / 4, 256, 0, stream>>>(offs, nbr, h1b, coef, b1, out1b);

  // layer 2:  h2 = out1 @ W2  (50000x256 @ 256x512), permuted cols, bf16 out
  k_gemm_bf<<<dim3((NN + 63) / 64, (NHEADS * NCLASS) / 256), 256, 0, stream>>>(
      out1b, W2t, h2b, NN, NHID, NHEADS * NCLASS);
  k_escore_p<<<(NN * NHEADS + 255) / 256, 256, 0, stream>>>(h2b, a2s, a2d, es1, ed1);
  k_coef<<<(NN + 3) / 4, 256, 0, stream>>>(offs, nbr, es1, ed1, coef);
  k_agg2<<<(NN + 3) / 4, 256, 0, stream>>>(offs, nbr, h2b, coef, b2, (float*)d_out);
}

// Round 7
// 647.657 us; speedup vs baseline: 1.8376x; 1.0467x over previous
//
#include <hip/hip_runtime.h>
#include <math.h>

#define NN 50000
#define NF 512
#define NHID 256
#define NCLASS 64
#define NHEADS 8

typedef __attribute__((ext_vector_type(8))) short bf16x8;
typedef __attribute__((ext_vector_type(4))) float f32x4;

static __device__ __forceinline__ unsigned short f2bf(float f) {
  unsigned int u = __float_as_uint(f);
  unsigned int r = (u + 0x7fffu + ((u >> 16) & 1u)) >> 16;
  return (unsigned short)r;
}
static __device__ __forceinline__ float bf2f(unsigned short u) {
  return __uint_as_float(((unsigned int)u) << 16);
}
static __device__ __forceinline__ float2 bfpair(unsigned int u) {
  return make_float2(__uint_as_float(u << 16), __uint_as_float(u & 0xffff0000u));
}

// ---------------- CSR build ----------------
__global__ void k_init_deg(int* deg) {
  int i = blockIdx.x * blockDim.x + threadIdx.x;
  if (i < NN) deg[i] = 1;  // self loop
}

__global__ void k_count(const int* __restrict__ dst, int E0, int* deg) {
  int i = blockIdx.x * blockDim.x + threadIdx.x;
  if (i < E0) atomicAdd(&deg[dst[i]], 1);
}

__global__ __launch_bounds__(1024) void k_scan(const int* __restrict__ deg, int* offs,
                                               int* cursor) {
  __shared__ int wbase[16];
  __shared__ int srun;
  int tid = threadIdx.x;
  int lane = tid & 63;
  int wv = tid >> 6;
  if (tid == 0) srun = 0;
  __syncthreads();
  for (int base = 0; base < NN; base += 4096) {
    int i = base + tid * 4;
    int4 v;
    if (i + 3 < NN) {
      v = *(const int4*)(deg + i);
    } else {
      v.x = (i + 0 < NN) ? deg[i + 0] : 0;
      v.y = (i + 1 < NN) ? deg[i + 1] : 0;
      v.z = (i + 2 < NN) ? deg[i + 2] : 0;
      v.w = (i + 3 < NN) ? deg[i + 3] : 0;
    }
    int tot = v.x + v.y + v.z + v.w;
    int s = tot;
    #pragma unroll
    for (int o = 1; o < 64; o <<= 1) {
      int t = __shfl_up(s, o);
      if (lane >= o) s += t;
    }
    if (lane == 63) wbase[wv] = s;
    __syncthreads();
    if (tid == 0) {
      int run = srun;
      #pragma unroll
      for (int w2 = 0; w2 < 16; w2++) {
        int t = wbase[w2];
        wbase[w2] = run;
        run += t;
      }
      srun = run;
    }
    __syncthreads();
    int p = wbase[wv] + s - tot;
    if (i + 0 < NN) { offs[i + 0] = p; cursor[i + 0] = p; p += v.x; }
    if (i + 1 < NN) { offs[i + 1] = p; cursor[i + 1] = p; p += v.y; }
    if (i + 2 < NN) { offs[i + 2] = p; cursor[i + 2] = p; p += v.z; }
    if (i + 3 < NN) { offs[i + 3] = p; cursor[i + 3] = p; }
  }
  __syncthreads();
  if (tid == 0) offs[NN] = srun;
}

__global__ void k_scatter(const int* __restrict__ src, const int* __restrict__ dst,
                          int E0, int* cursor, int* __restrict__ nbr) {
  int i = blockIdx.x * blockDim.x + threadIdx.x;
  if (i < E0) {
    int pos = atomicAdd(&cursor[dst[i]], 1);
    nbr[pos] = src[i];
  } else if (i < E0 + NN) {
    int v = i - E0;
    int pos = atomicAdd(&cursor[v], 1);
    nbr[pos] = v;
  }
}

// ---------------- casts ----------------
__global__ void k_cast4(const float* __restrict__ in, unsigned short* __restrict__ out,
                        int n4) {
  int i = blockIdx.x * blockDim.x + threadIdx.x;
  if (i >= n4) return;
  float4 v = *(const float4*)(in + (size_t)i * 4);
  ushort4 o;
  o.x = f2bf(v.x); o.y = f2bf(v.y); o.z = f2bf(v.z); o.w = f2bf(v.w);
  *(ushort4*)(out + (size_t)i * 4) = o;
}

__global__ void k_castWt(const float* __restrict__ W, unsigned short* __restrict__ Wt,
                         int K, int cols) {
  int i = blockIdx.x * blockDim.x + threadIdx.x;
  if (i >= K * cols) return;
  int k = i / cols, c = i % cols;
  Wt[(size_t)c * K + k] = f2bf(W[i]);
}

__global__ void k_castWt_perm(const float* __restrict__ W, unsigned short* __restrict__ Wt,
                              int K) {
  int i = blockIdx.x * blockDim.x + threadIdx.x;
  if (i >= K * NHEADS * NCLASS) return;
  int k = i / (NHEADS * NCLASS);
  int rem = i % (NHEADS * NCLASS);
  int h = rem / NCLASS, c = rem % NCLASS;
  Wt[(size_t)(c * NHEADS + h) * K + k] = f2bf(W[i]);
}

// ---------------- bf16 MFMA GEMM, LDS-staged B, bf16 output ----------------
__global__ __launch_bounds__(256) void k_gemm_bf(const unsigned short* __restrict__ A,
                                                 const unsigned short* __restrict__ Bt,
                                                 unsigned short* __restrict__ C,
                                                 int rows, int K, int cols) {
  __shared__ unsigned short Bs[256 * 40];  // 20 KB
  int t = threadIdx.x;
  int wave = t >> 6, lane = t & 63;
  int quad = lane >> 4, sixt = lane & 15;
  int rb = blockIdx.x * 64 + (wave >> 1) * 32;
  int cw = (wave & 1) * 128;
  int cbw = blockIdx.y * 256 + cw;
  int r0 = rb + sixt, r1 = rb + 16 + sixt;
  const unsigned short* Ap0 = A + (size_t)(r0 < rows ? r0 : 0) * K + quad * 8;
  const unsigned short* Ap1 = A + (size_t)(r1 < rows ? r1 : 0) * K + quad * 8;
  const unsigned short* Bg = Bt + (size_t)(blockIdx.y * 256 + (t >> 2)) * K + (t & 3) * 8;
  const size_t BgStep = (size_t)64 * K;
  char* BsW = (char*)Bs + (t >> 2) * 80 + (t & 3) * 16;
  f32x4 acc0[8] = {}, acc1[8] = {};
  for (int k0 = 0; k0 < K; k0 += 32) {
    uint4 v0 = *(const uint4*)(Bg + k0);
    uint4 v1 = *(const uint4*)(Bg + BgStep + k0);
    uint4 v2 = *(const uint4*)(Bg + 2 * BgStep + k0);
    uint4 v3 = *(const uint4*)(Bg + 3 * BgStep + k0);
    bf16x8 a0 = *(const bf16x8*)(Ap0 + k0);
    bf16x8 a1 = *(const bf16x8*)(Ap1 + k0);
    *(uint4*)(BsW) = v0;
    *(uint4*)(BsW + 64 * 80) = v1;
    *(uint4*)(BsW + 128 * 80) = v2;
    *(uint4*)(BsW + 192 * 80) = v3;
    __syncthreads();
    #pragma unroll
    for (int g = 0; g < 8; g++) {
      bf16x8 b = *(const bf16x8*)((const char*)Bs + (cw + g * 16 + sixt) * 80 + quad * 16);
      acc0[g] = __builtin_amdgcn_mfma_f32_16x16x32_bf16(a0, b, acc0[g], 0, 0, 0);
      acc1[g] = __builtin_amdgcn_mfma_f32_16x16x32_bf16(a1, b, acc1[g], 0, 0, 0);
    }
    __syncthreads();
  }
  #pragma unroll
  for (int r = 0; r < 4; r++) {
    int row = rb + quad * 4 + r;
    if (row < rows) {
      unsigned short* out = C + (size_t)row * cols + cbw + sixt;
      #pragma unroll
      for (int g = 0; g < 8; g++) out[g * 16] = f2bf(acc0[g][r]);
    }
    int row2 = row + 16;
    if (row2 < rows) {
      unsigned short* out = C + (size_t)row2 * cols + cbw + sixt;
      #pragma unroll
      for (int g = 0; g < 8; g++) out[g * 16] = f2bf(acc1[g][r]);
    }
  }
}

// ---------------- edge-score dots, contiguous layout (layer 1) ----------------
template <int C>
__global__ void k_escore_c(const unsigned short* __restrict__ h,
                           const float* __restrict__ asr, const float* __restrict__ ads,
                           float* __restrict__ es, float* __restrict__ ed) {
  int idx = blockIdx.x * blockDim.x + threadIdx.x;  // n*8 + head
  if (idx >= NN * NHEADS) return;
  int hd = idx & 7;
  const unsigned short* row = h + (size_t)idx * C;
  float s = 0.f, d = 0.f;
  #pragma unroll
  for (int c8 = 0; c8 < C / 8; c8++) {
    uint4 raw = *(const uint4*)(row + c8 * 8);
    float2 p0 = bfpair(raw.x), p1 = bfpair(raw.y), p2 = bfpair(raw.z), p3 = bfpair(raw.w);
    const float* as_ = asr + hd * C + c8 * 8;
    const float* ad_ = ads + hd * C + c8 * 8;
    s += p0.x * as_[0] + p0.y * as_[1] + p1.x * as_[2] + p1.y * as_[3] +
         p2.x * as_[4] + p2.y * as_[5] + p3.x * as_[6] + p3.y * as_[7];
    d += p0.x * ad_[0] + p0.y * ad_[1] + p1.x * ad_[2] + p1.y * ad_[3] +
         p2.x * ad_[4] + p2.y * ad_[5] + p3.x * ad_[6] + p3.y * ad_[7];
  }
  es[idx] = s;
  ed[idx] = d;
}

// ---------------- edge-score dots, permuted layout (layer 2) ----------------
__global__ void k_escore_p(const unsigned short* __restrict__ h,
                           const float* __restrict__ asr, const float* __restrict__ ads,
                           float* __restrict__ es, float* __restrict__ ed) {
  int idx = blockIdx.x * blockDim.x + threadIdx.x;  // n*8 + head
  if (idx >= NN * NHEADS) return;
  int hd = idx & 7;
  int n = idx >> 3;
  const unsigned short* row = h + (size_t)n * (NHEADS * NCLASS) + hd;
  float s = 0.f, d = 0.f;
  #pragma unroll
  for (int c = 0; c < NCLASS; c++) {
    float v = bf2f(row[c * NHEADS]);
    s += v * asr[hd * NCLASS + c];
    d += v * ads[hd * NCLASS + c];
  }
  es[idx] = s;
  ed[idx] = d;
}

// ---------------- fused softmax + layer-1 aggregation ----------------
// Sweep 1 (lane = sub*8+h): gather es, online (m,z), butterfly over subs.
// Sweep 2 (lane = head*8 | chan): re-gather es (L1-hot), coef inline, gather h1.
__global__ __launch_bounds__(256) void k_agg1f(const int* __restrict__ offs,
                                               const int* __restrict__ nbr,
                                               const unsigned short* __restrict__ h1,
                                               const float* __restrict__ es,
                                               const float* __restrict__ ed,
                                               const float* __restrict__ b1,
                                               unsigned short* __restrict__ out) {
  int node = blockIdx.x * 4 + (threadIdx.x >> 6);
  if (node >= NN) return;
  int lane = threadIdx.x & 63;
  int h = lane & 7;
  int beg = offs[node], end = offs[node + 1];
  float edst = ed[node * NHEADS + h];
  float m = -1e30f, z = 0.f;
  for (int k = beg + (lane >> 3); k < end; k += 8) {
    int s = nbr[k];
    float a = es[s * NHEADS + h] + edst;
    a = (a > 0.f) ? a : 0.2f * a;
    float mn = fmaxf(m, a);
    z = z * __expf(m - mn) + __expf(a - mn);
    m = mn;
  }
  #pragma unroll
  for (int o = 8; o < 64; o <<= 1) {
    float m2 = __shfl_xor(m, o);
    float z2 = __shfl_xor(z, o);
    float mn = fmaxf(m, m2);
    z = z * __expf(m - mn) + z2 * __expf(m2 - mn);
    m = mn;
  }
  float inv = 1.f / z;
  // redistribute per-head state to sweep-2 mapping (head = lane>>3)
  int head = lane >> 3;
  float mh = __shfl(m, head);
  float ivh = __shfl(inv, head);
  float edh = __shfl(edst, head);
  float4 acc = make_float4(0.f, 0.f, 0.f, 0.f);
  int k = beg;
  for (; k + 1 < end; k += 2) {
    int s0 = nbr[k], s1 = nbr[k + 1];
    float a0 = es[s0 * NHEADS + head] + edh;
    float a1c = es[s1 * NHEADS + head] + edh;
    a0 = (a0 > 0.f) ? a0 : 0.2f * a0;
    a1c = (a1c > 0.f) ? a1c : 0.2f * a1c;
    float c0 = __expf(a0 - mh) * ivh;
    float c1 = __expf(a1c - mh) * ivh;
    uint2 r0 = *(const uint2*)(h1 + (size_t)s0 * NHID + (lane << 2));
    uint2 r1 = *(const uint2*)(h1 + (size_t)s1 * NHID + (lane << 2));
    float2 p0 = bfpair(r0.x), p1 = bfpair(r0.y);
    float2 q0 = bfpair(r1.x), q1 = bfpair(r1.y);
    acc.x += c0 * p0.x + c1 * q0.x;
    acc.y += c0 * p0.y + c1 * q0.y;
    acc.z += c0 * p1.x + c1 * q1.x;
    acc.w += c0 * p1.y + c1 * q1.y;
  }
  if (k < end) {
    int s0 = nbr[k];
    float a0 = es[s0 * NHEADS + head] + edh;
    a0 = (a0 > 0.f) ? a0 : 0.2f * a0;
    float c0 = __expf(a0 - mh) * ivh;
    uint2 r0 = *(const uint2*)(h1 + (size_t)s0 * NHID + (lane << 2));
    float2 p0 = bfpair(r0.x), p1 = bfpair(r0.y);
    acc.x += c0 * p0.x;
    acc.y += c0 * p0.y;
    acc.z += c0 * p1.x;
    acc.w += c0 * p1.y;
  }
  int col = lane << 2;
  ushort4 o;
  o.x = f2bf(fmaxf(acc.x + b1[col + 0], 0.f));
  o.y = f2bf(fmaxf(acc.y + b1[col + 1], 0.f));
  o.z = f2bf(fmaxf(acc.z + b1[col + 2], 0.f));
  o.w = f2bf(fmaxf(acc.w + b1[col + 3], 0.f));
  *(ushort4*)(out + (size_t)node * NHID + col) = o;
}

// ---------------- fused softmax + layer-2 aggregation + mean + log_softmax ----------
// Sweep 1 as agg1f. Sweep 2: 8-edge groups; lanes compute the 64 (edge,head)
// coefs (1 exp/lane), stage in per-wave LDS, then gather h2 rows (16B/lane).
__global__ __launch_bounds__(256) void k_agg2f(const int* __restrict__ offs,
                                               const int* __restrict__ nbr,
                                               const unsigned short* __restrict__ h2,
                                               const float* __restrict__ es,
                                               const float* __restrict__ ed,
                                               const float* __restrict__ b2,
                                               float* __restrict__ out) {
  __shared__ float cs[4][64];
  int wv = threadIdx.x >> 6;
  int node = blockIdx.x * 4 + wv;
  if (node >= NN) return;
  int lane = threadIdx.x & 63;
  int h = lane & 7;
  int sub = lane >> 3;
  int beg = offs[node], end = offs[node + 1];
  float edst = ed[node * NHEADS + h];
  float m = -1e30f, z = 0.f;
  for (int k = beg + sub; k < end; k += 8) {
    int s = nbr[k];
    float a = es[s * NHEADS + h] + edst;
    a = (a > 0.f) ? a : 0.2f * a;
    float mn = fmaxf(m, a);
    z = z * __expf(m - mn) + __expf(a - mn);
    m = mn;
  }
  #pragma unroll
  for (int o = 8; o < 64; o <<= 1) {
    float m2 = __shfl_xor(m, o);
    float z2 = __shfl_xor(z, o);
    float mn = fmaxf(m, m2);
    z = z * __expf(m - mn) + z2 * __expf(m2 - mn);
    m = mn;
  }
  float inv = 1.f / z;
  float acc[8] = {};
  for (int kb = beg; kb < end; kb += 8) {
    // stage: lane handles (edge kb+sub, head h)
    int ki = kb + sub;
    int s = nbr[ki < end ? ki : end - 1];
    float a = es[s * NHEADS + h] + edst;
    a = (a > 0.f) ? a : 0.2f * a;
    float c = __expf(a - m) * inv;
    cs[wv][sub * 8 + h] = (ki < end) ? c : 0.f;
    int cnt = end - kb;
    if (cnt > 8) cnt = 8;
    for (int e = 0; e < cnt; e++) {
      int se = nbr[kb + e];
      float4 cA = *(const float4*)&cs[wv][e * 8];
      float4 cB = *(const float4*)&cs[wv][e * 8 + 4];
      uint4 r = *(const uint4*)(h2 + (size_t)se * (NHEADS * NCLASS) + (lane << 3));
      float2 p0 = bfpair(r.x), p1 = bfpair(r.y), p2 = bfpair(r.z), p3 = bfpair(r.w);
      acc[0] += cA.x * p0.x;
      acc[1] += cA.y * p0.y;
      acc[2] += cA.z * p1.x;
      acc[3] += cA.w * p1.y;
      acc[4] += cB.x * p2.x;
      acc[5] += cB.y * p2.y;
      acc[6] += cB.z * p3.x;
      acc[7] += cB.w * p3.y;
    }
  }
  float val = 0.f;
  #pragma unroll
  for (int hh = 0; hh < 8; hh++) val += acc[hh];
  val = val * 0.125f + b2[lane];
  float mx = val;
  #pragma unroll
  for (int o = 32; o > 0; o >>= 1) mx = fmaxf(mx, __shfl_xor(mx, o));
  float ex = __expf(val - mx);
  float sm = ex;
  #pragma unroll
  for (int o = 32; o > 0; o >>= 1) sm += __shfl_xor(sm, o);
  out[(size_t)node * NCLASS + lane] = val - mx - __logf(sm);
}

// ---------------- launch ----------------
extern "C" void kernel_launch(void* const* d_in, const int* in_sizes, int n_in,
                              void* d_out, int out_size, void* d_ws, size_t ws_size,
                              hipStream_t stream) {
  const float* x   = (const float*)d_in[0];
  const int* eidx  = (const int*)d_in[1];
  const float* W1  = (const float*)d_in[2];
  const float* a1s = (const float*)d_in[3];
  const float* a1d = (const float*)d_in[4];
  const float* b1  = (const float*)d_in[5];
  const float* W2  = (const float*)d_in[6];
  const float* a2s = (const float*)d_in[7];
  const float* a2d = (const float*)d_in[8];
  const float* b2  = (const float*)d_in[9];
  const int E0 = in_sizes[1] / 2;
  const int* esrc = eidx;
  const int* edst = eidx + E0;
  const int E = E0 + NN;

  char* w = (char*)d_ws;
  auto carve = [&](size_t bytes) {
    void* p = (void*)w;
    w += (bytes + 255) & ~(size_t)255;
    return p;
  };
  int* deg      = (int*)carve((size_t)NN * 4);
  int* offs     = (int*)carve((size_t)(NN + 1) * 4);
  int* cursor   = (int*)carve((size_t)NN * 4);
  int* nbr      = (int*)carve((size_t)E * 4);
  float* es1    = (float*)carve((size_t)NN * NHEADS * 4);
  float* ed1    = (float*)carve((size_t)NN * NHEADS * 4);
  unsigned short* xbf   = (unsigned short*)carve((size_t)NN * NF * 2);
  unsigned short* W1t   = (unsigned short*)carve((size_t)NF * NHID * 2);
  unsigned short* W2t   = (unsigned short*)carve((size_t)NHID * NHEADS * NCLASS * 2);
  unsigned short* h1b   = (unsigned short*)carve((size_t)NN * NHID * 2);
  unsigned short* out1b = (unsigned short*)carve((size_t)NN * NHID * 2);
  unsigned short* h2b   = (unsigned short*)carve((size_t)NN * NHEADS * NCLASS * 2);

  // CSR build
  k_init_deg<<<(NN + 255) / 256, 256, 0, stream>>>(deg);
  k_count<<<(E0 + 255) / 256, 256, 0, stream>>>(edst, E0, deg);
  k_scan<<<1, 1024, 0, stream>>>(deg, offs, cursor);
  k_scatter<<<(E0 + NN + 255) / 256, 256, 0, stream>>>(esrc, edst, E0, cursor, nbr);

  // casts
  k_cast4<<<(NN * NF / 4 + 255) / 256, 256, 0, stream>>>(x, xbf, NN * NF / 4);
  k_castWt<<<(NF * NHID + 255) / 256, 256, 0, stream>>>(W1, W1t, NF, NHID);
  k_castWt_perm<<<(NHID * NHEADS * NCLASS + 255) / 256, 256, 0, stream>>>(W2, W2t, NHID);

  // layer 1
  k_gemm_bf<<<dim3((NN + 63) / 64, NHID / 256), 256, 0, stream>>>(xbf, W1t, h1b,
                                                                  NN, NF, NHID);
  k_escore_c<32><<<(NN * NHEADS + 255) / 256, 256, 0, stream>>>(h1b, a1s, a1d, es1, ed1);
  k_agg1f<<<(NN + 3) / 4, 256, 0, stream>>>(offs, nbr, h1b, es1, ed1, b1, out1b);

  // layer 2
  k_gemm_bf<<<dim3((NN + 63) / 64, (NHEADS * NCLASS) / 256), 256, 0, stream>>>(
      out1b, W2t, h2b, NN, NHID, NHEADS * NCLASS);
  k_escore_p<<<(NN * NHEADS + 255) / 256, 256, 0, stream>>>(h2b, a2s, a2d, es1, ed1);
  k_agg2f<<<(NN + 3) / 4, 256, 0, stream>>>(offs, nbr, h2b, es1, ed1, b2, (float*)d_out);
}